// Round 1
// baseline (143.449 us; speedup 1.0000x reference)
//
#include <hip/hip_runtime.h>

// ---------------- problem constants ----------------
// B=4, N=1024, C=256, H=8, HD=32, SCALE=HD^-0.5
#define LOG2E 1.4426950408889634f

typedef __attribute__((ext_vector_type(8))) short bf16x8_t;   // 8 bf16 (4 VGPRs) — mfma A/B frag
typedef __attribute__((ext_vector_type(4))) float f32x4_t;    // mfma C/D frag

#if __has_builtin(__builtin_amdgcn_exp2f)
#define EXP2F(x) __builtin_amdgcn_exp2f(x)
#else
#define EXP2F(x) exp2f(x)
#endif

__device__ __forceinline__ unsigned short f2bf(float f) {
    unsigned u = __float_as_uint(f);
    u += 0x7fffu + ((u >> 16) & 1u);      // RNE
    return (unsigned short)(u >> 16);
}

// ---------------- kernel 1: f32 -> bf16 conversions (weights transposed) ----------------
__global__ __launch_bounds__(256) void k_convert(
    const float* __restrict__ x, const float* __restrict__ Wqk,
    const float* __restrict__ Wv, const float* __restrict__ Wpj,
    unsigned short* __restrict__ x_bf, unsigned short* __restrict__ Wqk_t,
    unsigned short* __restrict__ Wv_t, unsigned short* __restrict__ Wp_t)
{
    int tid = blockIdx.x * 256 + threadIdx.x;
    int stride = gridDim.x * 256;
    // x: 4096x256 f32 -> bf16 (vectorized: 4 f32 -> 8B)
    for (int i = tid; i < 4096 * 256 / 4; i += stride) {
        float4 v = ((const float4*)x)[i];
        uint2 o;
        o.x = (unsigned)f2bf(v.x) | ((unsigned)f2bf(v.y) << 16);
        o.y = (unsigned)f2bf(v.z) | ((unsigned)f2bf(v.w) << 16);
        ((uint2*)x_bf)[i] = o;
    }
    // W_qk [256][512] -> Wqk_t [n=512][k=256]
    for (int i = tid; i < 256 * 512; i += stride) { int k = i >> 9, n = i & 511; Wqk_t[n * 256 + k] = f2bf(Wqk[i]); }
    // W_v [256][256] -> Wv_t [n][k]
    for (int i = tid; i < 256 * 256; i += stride) { int k = i >> 8, n = i & 255; Wv_t[n * 256 + k] = f2bf(Wv[i]); }
    // W_proj [256][256] -> Wp_t [n][k]
    for (int i = tid; i < 256 * 256; i += stride) { int k = i >> 8, n = i & 255; Wp_t[n * 256 + k] = f2bf(Wpj[i]); }
}

// ---------------- kernel 2: QKV projection GEMM (M=4096, N=768, K=256) ----------------
// q written pre-scaled by SCALE*log2(e) as bf16 [bh][n][d]
// k written bf16 [bh][n][d]; v written TRANSPOSED bf16 [bh][d][n]
__global__ __launch_bounds__(256) void k_qkv(
    const unsigned short* __restrict__ x_bf,
    const unsigned short* __restrict__ Wqk_t,
    const unsigned short* __restrict__ Wv_t,
    unsigned short* __restrict__ q_ws, unsigned short* __restrict__ k_ws,
    unsigned short* __restrict__ v_ws)
{
    __shared__ unsigned short Al[64 * 72];   // [row][k-chunk 64 +8 pad]
    __shared__ unsigned short Bl[64 * 72];   // [n][k-chunk 64 +8 pad]
    const int tid = threadIdx.x;
    const int n0 = blockIdx.x * 64;          // 0..11 -> col tile in 768
    const int row0 = blockIdx.y * 64;        // 0..63 -> row tile in 4096
    const int w = tid >> 6, lane = tid & 63;
    const int lhi = lane >> 4, llo = lane & 15;

    f32x4_t acc[4] = {};
    for (int kc = 0; kc < 4; ++kc) {
        int idx = tid;
        #pragma unroll
        for (int s = 0; s < 2; ++s, idx += 256) {
            int r = idx >> 3, c8 = idx & 7;
            *(uint4*)(&Al[r * 72 + c8 * 8]) =
                *(const uint4*)(x_bf + (row0 + r) * 256 + kc * 64 + c8 * 8);
        }
        idx = tid;
        #pragma unroll
        for (int s = 0; s < 2; ++s, idx += 256) {
            int r = idx >> 3, c8 = idx & 7;
            int ng = n0 + r;
            const unsigned short* src = (ng < 512) ? (Wqk_t + ng * 256) : (Wv_t + (ng - 512) * 256);
            *(uint4*)(&Bl[r * 72 + c8 * 8]) = *(const uint4*)(src + kc * 64 + c8 * 8);
        }
        __syncthreads();
        #pragma unroll
        for (int ks = 0; ks < 2; ++ks) {
            bf16x8_t a = *(const bf16x8_t*)(&Al[(w * 16 + llo) * 72 + ks * 32 + lhi * 8]);
            #pragma unroll
            for (int nt = 0; nt < 4; ++nt) {
                bf16x8_t b = *(const bf16x8_t*)(&Bl[(nt * 16 + llo) * 72 + ks * 32 + lhi * 8]);
                acc[nt] = __builtin_amdgcn_mfma_f32_16x16x32_bf16(a, b, acc[nt], 0, 0, 0);
            }
        }
        __syncthreads();
    }
    // epilogue: route to q (scaled), k, v(transposed)
    constexpr float QSC = (float)(1.4426950408889634 / 5.656854249492380195206754896838);
    #pragma unroll
    for (int nt = 0; nt < 4; ++nt) {
        int ng = n0 + nt * 16 + llo;
        #pragma unroll
        for (int r = 0; r < 4; ++r) {
            int ig = row0 + w * 16 + lhi * 4 + r;   // D: row=(lane>>4)*4+r, col=lane&15
            float val = acc[nt][r];
            int b = ig >> 10, i = ig & 1023;
            if (ng < 256) {
                int h = ng >> 5, d = ng & 31;
                q_ws[((b * 8 + h) * 1024 + i) * 32 + d] = f2bf(val * QSC);
            } else if (ng < 512) {
                int c = ng - 256, h = c >> 5, d = c & 31;
                k_ws[((b * 8 + h) * 1024 + i) * 32 + d] = f2bf(val);
            } else {
                int c = ng - 512, h = c >> 5, d = c & 31;
                v_ws[((b * 8 + h) * 32 + d) * 1024 + i] = f2bf(val);
            }
        }
    }
}

// ---------------- kernel 3: fused dual-softmax attention ----------------
// grid: 512 blocks = 32 (b,h) x 16 i-tiles (XCD-swizzled), 256 threads (4 waves x 16 rows)
__global__ __launch_bounds__(256) void k_attn(
    const unsigned short* __restrict__ q_ws,
    const unsigned short* __restrict__ k_ws,
    const unsigned short* __restrict__ v_ws,
    const float* __restrict__ coords,
    const float* __restrict__ W_pos,
    const float* __restrict__ b_pos,
    const float* __restrict__ gating,
    unsigned short* __restrict__ o_ws)
{
    __shared__ unsigned short Kl[64 * 40];   // K tile [j][d], rows padded to 40 bf16 (80B)
    __shared__ unsigned short Vt[32 * 72];   // V^T tile [d][j], rows padded to 72 bf16 (144B)
    __shared__ unsigned short Wp[64 * 72];   // exp(patch logit) [i][j]
    __shared__ unsigned short Wq[64 * 72];   // exp(pos logit)   [i][j]
    __shared__ float P3[1024 * 3];           // coords for this batch
    __shared__ float Lbuf[128];              // denominators

    const int tid = threadIdx.x;
    const int bid = blockIdx.x;
    // XCD swizzle: keep each (b,h)'s 256KB K/V resident in one XCD's L2
    const int s = bid >> 3;
    const int bh = (bid & 7) * 4 + (s >> 4);
    const int it = s & 15;
    const int b = bh >> 3, h = bh & 7;

    const int w = tid >> 6, lane = tid & 63;
    const int lhi = lane >> 4, llo = lane & 15;

    for (int i = tid; i < 3072; i += 256) P3[i] = coords[b * 3072 + i];

    const float wx = W_pos[0 * 8 + h] * LOG2E;
    const float wy = W_pos[1 * 8 + h] * LOG2E;
    const float wz = W_pos[2 * 8 + h] * LOG2E;
    const float wd = W_pos[3 * 8 + h] * LOG2E;
    const float bp = b_pos[h] * LOG2E;
    const float sig = 1.0f / (1.0f + __expf(-gating[h]));

    const int i_base = it * 64 + w * 16;
    // Q fragment: A[row=lane&15][k=(lane>>4)*8+e]; q pre-scaled by SCALE*log2e
    bf16x8_t qf = *(const bf16x8_t*)(q_ws + (bh * 1024 + i_base + llo) * 32 + lhi * 8);

    __syncthreads();   // coords staged
    float pix[4], piy[4], piz[4];
    #pragma unroll
    for (int r = 0; r < 4; ++r) {
        int i = i_base + lhi * 4 + r;
        pix[r] = P3[i * 3 + 0]; piy[r] = P3[i * 3 + 1]; piz[r] = P3[i * 3 + 2];
    }

    f32x4_t accP[2] = {};            // O^T_patch: [dt] -> D[row=d-local][col=i-local]
    f32x4_t accQ[2] = {};            // O^T_pos
    float lp[4] = {0, 0, 0, 0}, lq[4] = {0, 0, 0, 0};

    for (int t = 0; t < 16; ++t) {
        const int j0 = t * 64;
        {   // stage K [64][32] and V^T [32][64] tiles (bf16, padded rows)
            int r = tid >> 2, c = tid & 3;
            *(uint4*)(&Kl[r * 40 + c * 8]) =
                *(const uint4*)(k_ws + (bh * 1024 + j0 + r) * 32 + c * 8);
            int d = tid >> 3, jc = tid & 7;
            *(uint4*)(&Vt[d * 72 + jc * 8]) =
                *(const uint4*)(v_ws + (bh * 32 + d) * 1024 + j0 + jc * 8);
        }
        __syncthreads();

        // ---- QK^T (1 mfma per 16x16, K=32=HD) + pos logits + exp, write P tiles ----
        #pragma unroll
        for (int jq = 0; jq < 4; ++jq) {
            bf16x8_t kf = *(const bf16x8_t*)(&Kl[(jq * 16 + llo) * 40 + lhi * 8]);
            f32x4_t zero = {};
            f32x4_t sv = __builtin_amdgcn_mfma_f32_16x16x32_bf16(qf, kf, zero, 0, 0, 0);
            int jg = j0 + jq * 16 + llo;
            float pjx = P3[jg * 3 + 0], pjy = P3[jg * 3 + 1], pjz = P3[jg * 3 + 2];
            #pragma unroll
            for (int r = 0; r < 4; ++r) {
                float dx = pjx - pix[r], dy = pjy - piy[r], dz = pjz - piz[r];
                float d2 = fmaf(dx, dx, fmaf(dy, dy, dz * dz));
                float dist = sqrtf(d2);
                float spos = fmaf(wd, dist, fmaf(wz, dz, fmaf(wy, dy, fmaf(wx, dx, bp))));
                float ep = EXP2F(sv[r]);     // exp(q.k*scale): scale*log2e folded into q
                float eq = EXP2F(spos);      // exp(pos logit): log2e folded into w/bias
                lp[r] += ep; lq[r] += eq;
                int ib = w * 16 + lhi * 4 + r;
                Wp[ib * 72 + jq * 16 + llo] = f2bf(ep);
                Wq[ib * 72 + jq * 16 + llo] = f2bf(eq);
            }
        }

        // ---- PV: O^T[d][i] += V^T[d][j] * P[i][j]  (A=Vt frag, B=P frag) ----
        // P rows read are this wave's own rows -> same-wave LDS dependency, no barrier.
        #pragma unroll
        for (int jb = 0; jb < 2; ++jb) {
            bf16x8_t bP = *(const bf16x8_t*)(&Wp[(w * 16 + llo) * 72 + jb * 32 + lhi * 8]);
            bf16x8_t bQ = *(const bf16x8_t*)(&Wq[(w * 16 + llo) * 72 + jb * 32 + lhi * 8]);
            #pragma unroll
            for (int dt = 0; dt < 2; ++dt) {
                bf16x8_t af = *(const bf16x8_t*)(&Vt[(dt * 16 + llo) * 72 + jb * 32 + lhi * 8]);
                accP[dt] = __builtin_amdgcn_mfma_f32_16x16x32_bf16(af, bP, accP[dt], 0, 0, 0);
                accQ[dt] = __builtin_amdgcn_mfma_f32_16x16x32_bf16(af, bQ, accQ[dt], 0, 0, 0);
            }
        }
        __syncthreads();   // protect next tile's staging
    }

    // denominators: reduce over the 16 lanes (llo) sharing each row
    #pragma unroll
    for (int r = 0; r < 4; ++r) {
        #pragma unroll
        for (int m = 1; m <= 8; m <<= 1) {
            lp[r] += __shfl_xor(lp[r], m, 64);
            lq[r] += __shfl_xor(lq[r], m, 64);
        }
    }
    if (llo == 0) {
        #pragma unroll
        for (int r = 0; r < 4; ++r) {
            int ib = w * 16 + lhi * 4 + r;
            Lbuf[ib] = lp[r]; Lbuf[64 + ib] = lq[r];
        }
    }
    __syncthreads();

    float Lp = Lbuf[w * 16 + llo], Lq = Lbuf[64 + w * 16 + llo];
    float ca = (1.0f - sig) / Lp, cb = sig / Lq;
    int n_g = b * 1024 + i_base + llo;          // output row; sum(attn)==1 so no renorm
    #pragma unroll
    for (int dt = 0; dt < 2; ++dt) {
        float v0 = ca * accP[dt][0] + cb * accQ[dt][0];
        float v1 = ca * accP[dt][1] + cb * accQ[dt][1];
        float v2 = ca * accP[dt][2] + cb * accQ[dt][2];
        float v3 = ca * accP[dt][3] + cb * accQ[dt][3];
        uint2 uu;
        uu.x = (unsigned)f2bf(v0) | ((unsigned)f2bf(v1) << 16);
        uu.y = (unsigned)f2bf(v2) | ((unsigned)f2bf(v3) << 16);
        *(uint2*)(o_ws + n_g * 256 + h * 32 + dt * 16 + lhi * 4) = uu;
    }
}

// ---------------- kernel 4: output projection GEMM (M=4096, N=256, K=256) + bias ----------------
__global__ __launch_bounds__(256) void k_proj(
    const unsigned short* __restrict__ A,
    const unsigned short* __restrict__ Bt,
    const float* __restrict__ bias,
    float* __restrict__ out)
{
    __shared__ unsigned short Al[64 * 72];
    __shared__ unsigned short Bl[64 * 72];
    const int tid = threadIdx.x;
    const int n0 = blockIdx.x * 64;
    const int row0 = blockIdx.y * 64;
    const int w = tid >> 6, lane = tid & 63;
    const int lhi = lane >> 4, llo = lane & 15;

    f32x4_t acc[4] = {};
    for (int kc = 0; kc < 4; ++kc) {
        int idx = tid;
        #pragma unroll
        for (int s = 0; s < 2; ++s, idx += 256) {
            int r = idx >> 3, c8 = idx & 7;
            *(uint4*)(&Al[r * 72 + c8 * 8]) =
                *(const uint4*)(A + (row0 + r) * 256 + kc * 64 + c8 * 8);
        }
        idx = tid;
        #pragma unroll
        for (int s = 0; s < 2; ++s, idx += 256) {
            int r = idx >> 3, c8 = idx & 7;
            *(uint4*)(&Bl[r * 72 + c8 * 8]) =
                *(const uint4*)(Bt + (n0 + r) * 256 + kc * 64 + c8 * 8);
        }
        __syncthreads();
        #pragma unroll
        for (int ks = 0; ks < 2; ++ks) {
            bf16x8_t a = *(const bf16x8_t*)(&Al[(w * 16 + llo) * 72 + ks * 32 + lhi * 8]);
            #pragma unroll
            for (int nt = 0; nt < 4; ++nt) {
                bf16x8_t b = *(const bf16x8_t*)(&Bl[(nt * 16 + llo) * 72 + ks * 32 + lhi * 8]);
                acc[nt] = __builtin_amdgcn_mfma_f32_16x16x32_bf16(a, b, acc[nt], 0, 0, 0);
            }
        }
        __syncthreads();
    }
    #pragma unroll
    for (int nt = 0; nt < 4; ++nt) {
        int ng = n0 + nt * 16 + llo;
        float bv = bias[ng];
        #pragma unroll
        for (int r = 0; r < 4; ++r) {
            int ig = row0 + w * 16 + lhi * 4 + r;
            out[ig * 256 + ng] = acc[nt][r] + bv;
        }
    }
}

// ---------------- launcher ----------------
extern "C" void kernel_launch(void* const* d_in, const int* in_sizes, int n_in,
                              void* d_out, int out_size, void* d_ws, size_t ws_size,
                              hipStream_t stream)
{
    const float* x    = (const float*)d_in[0];
    const float* vc   = (const float*)d_in[1];
    const float* Wqk  = (const float*)d_in[2];
    const float* Wv   = (const float*)d_in[3];
    const float* Wpj  = (const float*)d_in[4];
    const float* bpj  = (const float*)d_in[5];
    const float* Wpos = (const float*)d_in[6];
    const float* bpos = (const float*)d_in[7];
    const float* gat  = (const float*)d_in[8];
    float* out = (float*)d_out;

    char* ws = (char*)d_ws;
    unsigned short* x_bf  = (unsigned short*)(ws + 0);          // 2 MB
    unsigned short* Wqk_t = (unsigned short*)(ws + 2097152);    // 256 KB
    unsigned short* Wv_t  = (unsigned short*)(ws + 2359296);    // 128 KB
    unsigned short* Wp_t  = (unsigned short*)(ws + 2490368);    // 128 KB
    unsigned short* q_ws  = (unsigned short*)(ws + 2621440);    // 2 MB
    unsigned short* k_ws  = (unsigned short*)(ws + 4718592);    // 2 MB
    unsigned short* v_ws  = (unsigned short*)(ws + 6815744);    // 2 MB (transposed)
    unsigned short* o_ws  = (unsigned short*)(ws + 8912896);    // 2 MB

    hipLaunchKernelGGL(k_convert, dim3(512), dim3(256), 0, stream,
                       x, Wqk, Wv, Wpj, x_bf, Wqk_t, Wv_t, Wp_t);
    hipLaunchKernelGGL(k_qkv, dim3(12, 64), dim3(256), 0, stream,
                       x_bf, Wqk_t, Wv_t, q_ws, k_ws, v_ws);
    hipLaunchKernelGGL(k_attn, dim3(512), dim3(256), 0, stream,
                       q_ws, k_ws, v_ws, vc, Wpos, bpos, gat, o_ws);
    hipLaunchKernelGGL(k_proj, dim3(4, 64), dim3(256), 0, stream,
                       o_ws, Wp_t, bpj, out);
}

// Round 2
// 133.040 us; speedup vs baseline: 1.0782x; 1.0782x over previous
//
#include <hip/hip_runtime.h>

// ---------------- problem constants ----------------
// B=4, N=1024, C=256, H=8, HD=32, SCALE=HD^-0.5
#define LOG2E 1.4426950408889634f

typedef __attribute__((ext_vector_type(8))) short bf16x8_t;   // 8 bf16 (4 VGPRs) — mfma A/B frag
typedef __attribute__((ext_vector_type(4))) float f32x4_t;    // mfma C/D frag

#if __has_builtin(__builtin_amdgcn_exp2f)
#define EXP2F_(x) __builtin_amdgcn_exp2f(x)
#else
__device__ __forceinline__ float EXP2F_(float x) {
    float r; asm volatile("v_exp_f32 %0, %1\ns_nop 1" : "=v"(r) : "v"(x)); return r;
}
#endif
#if __has_builtin(__builtin_amdgcn_sqrtf)
#define SQRTF_(x) __builtin_amdgcn_sqrtf(x)
#else
__device__ __forceinline__ float SQRTF_(float x) {
    float r; asm volatile("v_sqrt_f32 %0, %1\ns_nop 1" : "=v"(r) : "v"(x)); return r;
}
#endif

__device__ __forceinline__ unsigned short f2bf(float f) {
    unsigned u = __float_as_uint(f);
    u += 0x7fffu + ((u >> 16) & 1u);      // RNE
    return (unsigned short)(u >> 16);
}

// ---------------- kernel 1: x f32->bf16 + weight transposes (via LDS, coalesced out) ----------------
__global__ __launch_bounds__(256) void k_convert(
    const float* __restrict__ x, const float* __restrict__ Wqk,
    const float* __restrict__ Wv, const float* __restrict__ Wpj,
    unsigned short* __restrict__ x_bf, unsigned short* __restrict__ Wqk_t,
    unsigned short* __restrict__ Wv_t, unsigned short* __restrict__ Wp_t)
{
    __shared__ unsigned short T[64 * 72];
    const int bid = blockIdx.x, tid = threadIdx.x;
    if (bid < 64) {
        // 64x64 transpose tiles: W[k][n] f32 -> Wt[n][k] bf16
        const float* src; unsigned short* dst; int N_, kt, nt;
        if (bid < 32)      { src = Wqk; dst = Wqk_t; N_ = 512; kt = bid & 3; nt = bid >> 2; }
        else if (bid < 48) { int t = bid - 32; src = Wv;  dst = Wv_t; N_ = 256; kt = t & 3; nt = t >> 2; }
        else               { int t = bid - 48; src = Wpj; dst = Wp_t; N_ = 256; kt = t & 3; nt = t >> 2; }
        const int kr = tid >> 2, seg = tid & 3;
        #pragma unroll
        for (int u = 0; u < 4; ++u) {
            float4 v = *(const float4*)(src + (kt * 64 + kr) * N_ + nt * 64 + seg * 16 + u * 4);
            T[(seg * 16 + u * 4 + 0) * 72 + kr] = f2bf(v.x);
            T[(seg * 16 + u * 4 + 1) * 72 + kr] = f2bf(v.y);
            T[(seg * 16 + u * 4 + 2) * 72 + kr] = f2bf(v.z);
            T[(seg * 16 + u * 4 + 3) * 72 + kr] = f2bf(v.w);
        }
        __syncthreads();
        const int n = tid >> 2, s2 = tid & 3;
        uint4 a = *(uint4*)&T[n * 72 + s2 * 16];
        uint4 b2 = *(uint4*)&T[n * 72 + s2 * 16 + 8];
        *(uint4*)(dst + (nt * 64 + n) * 256 + kt * 64 + s2 * 16) = a;
        *(uint4*)(dst + (nt * 64 + n) * 256 + kt * 64 + s2 * 16 + 8) = b2;
    } else {
        // x convert: 32 blocks x 32768 f32
        const int cb2 = bid - 64;
        const float4* xs = (const float4*)x + (size_t)cb2 * 8192;
        uint2* xd = (uint2*)x_bf + (size_t)cb2 * 8192;
        for (int i = tid; i < 8192; i += 256) {
            float4 v = xs[i];
            uint2 o;
            o.x = (unsigned)f2bf(v.x) | ((unsigned)f2bf(v.y) << 16);
            o.y = (unsigned)f2bf(v.z) | ((unsigned)f2bf(v.w) << 16);
            xd[i] = o;
        }
    }
}

// ---------------- kernel 2: QKV projection GEMM (M=4096, N=768, K=256) ----------------
// q pre-scaled by SCALE*log2e, [bh][n][d]; k [bh][n][d]; v [bh][n][d] (row-major, coalesced)
__global__ __launch_bounds__(256) void k_qkv(
    const unsigned short* __restrict__ x_bf,
    const unsigned short* __restrict__ Wqk_t,
    const unsigned short* __restrict__ Wv_t,
    unsigned short* __restrict__ q_ws, unsigned short* __restrict__ k_ws,
    unsigned short* __restrict__ v_ws)
{
    __shared__ unsigned short Al[64 * 72];
    __shared__ unsigned short Bl[64 * 72];
    const int tid = threadIdx.x;
    const int n0 = blockIdx.x * 64;
    const int row0 = blockIdx.y * 64;
    const int w = tid >> 6, lane = tid & 63;
    const int lhi = lane >> 4, llo = lane & 15;

    f32x4_t acc[4] = {};
    for (int kc = 0; kc < 4; ++kc) {
        int idx = tid;
        #pragma unroll
        for (int s = 0; s < 2; ++s, idx += 256) {
            int r = idx >> 3, c8 = idx & 7;
            *(uint4*)(&Al[r * 72 + c8 * 8]) =
                *(const uint4*)(x_bf + (row0 + r) * 256 + kc * 64 + c8 * 8);
        }
        idx = tid;
        #pragma unroll
        for (int s = 0; s < 2; ++s, idx += 256) {
            int r = idx >> 3, c8 = idx & 7;
            int ng = n0 + r;
            const unsigned short* src = (ng < 512) ? (Wqk_t + ng * 256) : (Wv_t + (ng - 512) * 256);
            *(uint4*)(&Bl[r * 72 + c8 * 8]) = *(const uint4*)(src + kc * 64 + c8 * 8);
        }
        __syncthreads();
        #pragma unroll
        for (int ks = 0; ks < 2; ++ks) {
            bf16x8_t a = *(const bf16x8_t*)(&Al[(w * 16 + llo) * 72 + ks * 32 + lhi * 8]);
            #pragma unroll
            for (int nt = 0; nt < 4; ++nt) {
                bf16x8_t b = *(const bf16x8_t*)(&Bl[(nt * 16 + llo) * 72 + ks * 32 + lhi * 8]);
                acc[nt] = __builtin_amdgcn_mfma_f32_16x16x32_bf16(a, b, acc[nt], 0, 0, 0);
            }
        }
        __syncthreads();
    }
    constexpr float QSC = (float)(1.4426950408889634 / 5.656854249492380195206754896838);
    #pragma unroll
    for (int nt = 0; nt < 4; ++nt) {
        int ng = n0 + nt * 16 + llo;
        #pragma unroll
        for (int r = 0; r < 4; ++r) {
            int ig = row0 + w * 16 + lhi * 4 + r;
            float val = acc[nt][r];
            int b = ig >> 10, i = ig & 1023;
            if (ng < 256) {
                int h = ng >> 5, d = ng & 31;
                q_ws[((b * 8 + h) * 1024 + i) * 32 + d] = f2bf(val * QSC);
            } else if (ng < 512) {
                int c = ng - 256, h = c >> 5, d = c & 31;
                k_ws[((b * 8 + h) * 1024 + i) * 32 + d] = f2bf(val);
            } else {
                int c = ng - 512, h = c >> 5, d = c & 31;
                v_ws[((b * 8 + h) * 1024 + i) * 32 + d] = f2bf(val);
            }
        }
    }
}

// ---------------- kernel 3: fused dual-softmax attention, J-split=2, f32 partials ----------------
// grid: 1024 blocks = 32 bh x 16 it x 2 jh (XCD-swizzled), 256 threads
// partial layout per (bh,it,jh), stride 4224 f32: [0..2047] Op^T[d][i], [2048..4095] Oq^T,
//                                                 [4096..4159] Lp[i], [4160..4223] Lq[i]
__global__ __launch_bounds__(256) void k_attn(
    const unsigned short* __restrict__ q_ws,
    const unsigned short* __restrict__ k_ws,
    const unsigned short* __restrict__ v_ws,
    const float* __restrict__ coords,
    const float* __restrict__ W_pos,
    const float* __restrict__ b_pos,
    float* __restrict__ part)
{
    __shared__ unsigned short Kl[64 * 40];   // K tile [j][d], row 40 shorts
    __shared__ unsigned short Vt[32 * 72];   // V^T tile [d][j], row 72 shorts
    __shared__ unsigned short Wp[64 * 72];   // exp(patch logit) [i][j]
    __shared__ unsigned short Wq[64 * 72];   // exp(pos logit)   [i][j]

    const int tid = threadIdx.x;
    const int bid = blockIdx.x;
    // XCD swizzle: 128 consecutive-per-XCD slots -> 4 bh per XCD, K/V stay L2-resident
    const int xcd = bid & 7, idx = bid >> 3;
    const int bh = xcd * 4 + (idx >> 5);
    const int rem = idx & 31;
    const int it = rem >> 1;
    const int jh = rem & 1;
    const int b = bh >> 3, h = bh & 7;

    const int w = tid >> 6, lane = tid & 63;
    const int lhi = lane >> 4, llo = lane & 15;

    const float wx = W_pos[0 * 8 + h] * LOG2E;
    const float wy = W_pos[1 * 8 + h] * LOG2E;
    const float wz = W_pos[2 * 8 + h] * LOG2E;
    const float wd = W_pos[3 * 8 + h] * LOG2E;
    const float bp = b_pos[h] * LOG2E;

    const int i_base = it * 64 + w * 16;
    bf16x8_t qf = *(const bf16x8_t*)(q_ws + (bh * 1024 + i_base + llo) * 32 + lhi * 8);

    const float* cb_ = coords + b * 3072;
    float pix[4], piy[4], piz[4];
    #pragma unroll
    for (int r = 0; r < 4; ++r) {
        int i = i_base + lhi * 4 + r;
        pix[r] = cb_[i * 3 + 0]; piy[r] = cb_[i * 3 + 1]; piz[r] = cb_[i * 3 + 2];
    }

    bf16x8_t ones;
    #pragma unroll
    for (int e = 0; e < 8; ++e) ones[e] = (short)0x3F80;   // bf16 1.0

    f32x4_t accP[2] = {}, accQ[2] = {};
    f32x4_t accLp = {}, accLq = {};

    for (int t = 0; t < 8; ++t) {
        const int j0 = jh * 512 + t * 64;
        {   // stage K [64][32] direct; V^T built by in-LDS transpose (conflict-free: lane==j)
            int r = tid >> 2, c = tid & 3;
            *(uint4*)(&Kl[r * 40 + c * 8]) =
                *(const uint4*)(k_ws + (bh * 1024 + j0 + r) * 32 + c * 8);
            uint4 vv = *(const uint4*)(v_ws + (bh * 1024 + j0 + lane) * 32 + w * 8);
            const unsigned short* pv = (const unsigned short*)&vv;
            #pragma unroll
            for (int e = 0; e < 8; ++e) Vt[(w * 8 + e) * 72 + lane] = pv[e];
        }
        __syncthreads();

        // ---- QK^T (MFMA) + pos logits + exp -> P tiles ----
        #pragma unroll
        for (int jq = 0; jq < 4; ++jq) {
            bf16x8_t kf = *(const bf16x8_t*)(&Kl[(jq * 16 + llo) * 40 + lhi * 8]);
            f32x4_t zero = {};
            f32x4_t sv = __builtin_amdgcn_mfma_f32_16x16x32_bf16(qf, kf, zero, 0, 0, 0);
            int jg = j0 + jq * 16 + llo;
            float pjx = cb_[jg * 3 + 0], pjy = cb_[jg * 3 + 1], pjz = cb_[jg * 3 + 2];
            #pragma unroll
            for (int r = 0; r < 4; ++r) {
                float dx = pjx - pix[r], dy = pjy - piy[r], dz = pjz - piz[r];
                float d2 = fmaf(dx, dx, fmaf(dy, dy, dz * dz));
                float dist = SQRTF_(d2);
                float spos = fmaf(wd, dist, fmaf(wz, dz, fmaf(wy, dy, fmaf(wx, dx, bp))));
                float ep = EXP2F_(sv[r]);
                float eq = EXP2F_(spos);
                int ib = w * 16 + lhi * 4 + r;
                Wp[ib * 72 + jq * 16 + llo] = f2bf(ep);
                Wq[ib * 72 + jq * 16 + llo] = f2bf(eq);
            }
        }

        // ---- PV MFMA + denominator rows via ones-vector MFMA ----
        #pragma unroll
        for (int jb = 0; jb < 2; ++jb) {
            bf16x8_t bP = *(const bf16x8_t*)(&Wp[(w * 16 + llo) * 72 + jb * 32 + lhi * 8]);
            bf16x8_t bQ = *(const bf16x8_t*)(&Wq[(w * 16 + llo) * 72 + jb * 32 + lhi * 8]);
            accLp = __builtin_amdgcn_mfma_f32_16x16x32_bf16(ones, bP, accLp, 0, 0, 0);
            accLq = __builtin_amdgcn_mfma_f32_16x16x32_bf16(ones, bQ, accLq, 0, 0, 0);
            #pragma unroll
            for (int dt = 0; dt < 2; ++dt) {
                bf16x8_t af = *(const bf16x8_t*)(&Vt[(dt * 16 + llo) * 72 + jb * 32 + lhi * 8]);
                accP[dt] = __builtin_amdgcn_mfma_f32_16x16x32_bf16(af, bP, accP[dt], 0, 0, 0);
                accQ[dt] = __builtin_amdgcn_mfma_f32_16x16x32_bf16(af, bQ, accQ[dt], 0, 0, 0);
            }
        }
        __syncthreads();
    }

    float* pb = part + (size_t)((bh * 16 + it) * 2 + jh) * 4224;
    #pragma unroll
    for (int dt = 0; dt < 2; ++dt) {
        #pragma unroll
        for (int r = 0; r < 4; ++r) {
            int d = dt * 16 + lhi * 4 + r;
            pb[d * 64 + w * 16 + llo] = accP[dt][r];
            pb[2048 + d * 64 + w * 16 + llo] = accQ[dt][r];
        }
    }
    if (lane < 16) {
        pb[4096 + w * 16 + lane] = accLp[0];
        pb[4160 + w * 16 + lane] = accLq[0];
    }
}

// ---------------- kernel 4: combine j-halves, normalize, gate -> o_ws bf16 ----------------
__global__ __launch_bounds__(256) void k_comb(
    const float* __restrict__ part, const float* __restrict__ gating,
    unsigned short* __restrict__ o_ws)
{
    const int bid = blockIdx.x;              // 512 = bh*16 + it
    const int bh = bid >> 4, it = bid & 15;
    const int b = bh >> 3, h = bh & 7;
    const int tid = threadIdx.x, w = tid >> 6, i = tid & 63;
    const float* p0 = part + (size_t)(bid * 2) * 4224;
    const float* p1 = p0 + 4224;
    float sig = 1.0f / (1.0f + __expf(-gating[h]));
    float Lp = p0[4096 + i] + p1[4096 + i];
    float Lq = p0[4160 + i] + p1[4160 + i];
    float ca = (1.0f - sig) / Lp, cb2 = sig / Lq;
    unsigned short ob[8];
    #pragma unroll
    for (int e = 0; e < 8; ++e) {
        int d = w * 8 + e;
        float Op = p0[d * 64 + i] + p1[d * 64 + i];
        float Oq = p0[2048 + d * 64 + i] + p1[2048 + d * 64 + i];
        ob[e] = f2bf(ca * Op + cb2 * Oq);
    }
    *(uint4*)(o_ws + ((size_t)(b * 1024 + it * 64 + i)) * 256 + h * 32 + w * 8) = *(uint4*)ob;
}

// ---------------- kernel 5: output projection GEMM (M=4096, N=256, K=256) + bias ----------------
__global__ __launch_bounds__(256) void k_proj(
    const unsigned short* __restrict__ A,
    const unsigned short* __restrict__ Bt,
    const float* __restrict__ bias,
    float* __restrict__ out)
{
    __shared__ unsigned short Al[64 * 72];
    __shared__ unsigned short Bl[64 * 72];
    const int tid = threadIdx.x;
    const int n0 = blockIdx.x * 64;
    const int row0 = blockIdx.y * 64;
    const int w = tid >> 6, lane = tid & 63;
    const int lhi = lane >> 4, llo = lane & 15;

    f32x4_t acc[4] = {};
    for (int kc = 0; kc < 4; ++kc) {
        int idx = tid;
        #pragma unroll
        for (int s = 0; s < 2; ++s, idx += 256) {
            int r = idx >> 3, c8 = idx & 7;
            *(uint4*)(&Al[r * 72 + c8 * 8]) =
                *(const uint4*)(A + (row0 + r) * 256 + kc * 64 + c8 * 8);
        }
        idx = tid;
        #pragma unroll
        for (int s = 0; s < 2; ++s, idx += 256) {
            int r = idx >> 3, c8 = idx & 7;
            *(uint4*)(&Bl[r * 72 + c8 * 8]) =
                *(const uint4*)(Bt + (n0 + r) * 256 + kc * 64 + c8 * 8);
        }
        __syncthreads();
        #pragma unroll
        for (int ks = 0; ks < 2; ++ks) {
            bf16x8_t a = *(const bf16x8_t*)(&Al[(w * 16 + llo) * 72 + ks * 32 + lhi * 8]);
            #pragma unroll
            for (int nt = 0; nt < 4; ++nt) {
                bf16x8_t b = *(const bf16x8_t*)(&Bl[(nt * 16 + llo) * 72 + ks * 32 + lhi * 8]);
                acc[nt] = __builtin_amdgcn_mfma_f32_16x16x32_bf16(a, b, acc[nt], 0, 0, 0);
            }
        }
        __syncthreads();
    }
    #pragma unroll
    for (int nt = 0; nt < 4; ++nt) {
        int ng = n0 + nt * 16 + llo;
        float bv = bias[ng];
        #pragma unroll
        for (int r = 0; r < 4; ++r) {
            int ig = row0 + w * 16 + lhi * 4 + r;
            out[ig * 256 + ng] = acc[nt][r] + bv;
        }
    }
}

// ---------------- launcher ----------------
extern "C" void kernel_launch(void* const* d_in, const int* in_sizes, int n_in,
                              void* d_out, int out_size, void* d_ws, size_t ws_size,
                              hipStream_t stream)
{
    const float* x    = (const float*)d_in[0];
    const float* vc   = (const float*)d_in[1];
    const float* Wqk  = (const float*)d_in[2];
    const float* Wv   = (const float*)d_in[3];
    const float* Wpj  = (const float*)d_in[4];
    const float* bpj  = (const float*)d_in[5];
    const float* Wpos = (const float*)d_in[6];
    const float* bpos = (const float*)d_in[7];
    const float* gat  = (const float*)d_in[8];
    float* out = (float*)d_out;

    char* ws = (char*)d_ws;
    unsigned short* x_bf  = (unsigned short*)(ws + 0);          // 2 MB
    unsigned short* Wqk_t = (unsigned short*)(ws + 2097152);    // 256 KB
    unsigned short* Wv_t  = (unsigned short*)(ws + 2359296);    // 128 KB
    unsigned short* Wp_t  = (unsigned short*)(ws + 2490368);    // 128 KB
    unsigned short* q_ws  = (unsigned short*)(ws + 2621440);    // 2 MB
    unsigned short* k_ws  = (unsigned short*)(ws + 4718592);    // 2 MB
    unsigned short* v_ws  = (unsigned short*)(ws + 6815744);    // 2 MB (row-major now)
    unsigned short* o_ws  = (unsigned short*)(ws + 8912896);    // 2 MB
    float*          partf = (float*)(ws + 11010048);            // 16.5 MB partials

    hipLaunchKernelGGL(k_convert, dim3(96), dim3(256), 0, stream,
                       x, Wqk, Wv, Wpj, x_bf, Wqk_t, Wv_t, Wp_t);
    hipLaunchKernelGGL(k_qkv, dim3(12, 64), dim3(256), 0, stream,
                       x_bf, Wqk_t, Wv_t, q_ws, k_ws, v_ws);
    hipLaunchKernelGGL(k_attn, dim3(1024), dim3(256), 0, stream,
                       q_ws, k_ws, v_ws, vc, Wpos, bpos, partf);
    hipLaunchKernelGGL(k_comb, dim3(512), dim3(256), 0, stream,
                       partf, gat, o_ws);
    hipLaunchKernelGGL(k_proj, dim3(4, 64), dim3(256), 0, stream,
                       o_ws, Wp_t, bpj, out);
}

// Round 3
// 125.667 us; speedup vs baseline: 1.1415x; 1.0587x over previous
//
#include <hip/hip_runtime.h>
#include <hip/hip_bf16.h>

// ---------------- problem constants ----------------
// B=4, N=1024, C=256, H=8, HD=32, SCALE=HD^-0.5
#define LOG2E 1.4426950408889634f

typedef __attribute__((ext_vector_type(8))) short bf16x8_t;   // 8 bf16 (4 VGPRs) — mfma A/B frag
typedef __attribute__((ext_vector_type(4))) float f32x4_t;    // mfma C/D frag

#if __has_builtin(__builtin_amdgcn_exp2f)
#define EXP2F_(x) __builtin_amdgcn_exp2f(x)
#else
__device__ __forceinline__ float EXP2F_(float x) {
    float r; asm volatile("v_exp_f32 %0, %1\ns_nop 1" : "=v"(r) : "v"(x)); return r;
}
#endif
#if __has_builtin(__builtin_amdgcn_sqrtf)
#define SQRTF_(x) __builtin_amdgcn_sqrtf(x)
#else
__device__ __forceinline__ float SQRTF_(float x) {
    float r; asm volatile("v_sqrt_f32 %0, %1\ns_nop 1" : "=v"(r) : "v"(x)); return r;
}
#endif

__device__ __forceinline__ unsigned short f2bf(float f) {
    unsigned u = __float_as_uint(f);
    u += 0x7fffu + ((u >> 16) & 1u);      // RNE
    return (unsigned short)(u >> 16);
}

// pack 2 f32 -> u32 of 2 bf16 (lo = first) — compiles to v_cvt_pk_bf16_f32
__device__ __forceinline__ unsigned pk2(float lo, float hi) {
    union { __hip_bfloat162 h2; unsigned u; } cvt;
    cvt.h2 = __float22bfloat162_rn(make_float2(lo, hi));
    return cvt.u;
}

// global(per-lane) -> LDS(wave base + lane*16) direct 16B copy
__device__ __forceinline__ void stage16(const unsigned short* g, unsigned short* l, int lane) {
#if __has_builtin(__builtin_amdgcn_global_load_lds)
    __builtin_amdgcn_global_load_lds((const __attribute__((address_space(1))) void*)g,
                                     (__attribute__((address_space(3))) void*)l, 16, 0, 0);
#else
    *(uint4*)((char*)l + lane * 16) = *(const uint4*)g;
#endif
}

// ---------------- kernel 1: x f32->bf16 + weight transposes (via LDS, coalesced out) ----------------
__global__ __launch_bounds__(256) void k_convert(
    const float* __restrict__ x, const float* __restrict__ Wqk,
    const float* __restrict__ Wv, const float* __restrict__ Wpj,
    unsigned short* __restrict__ x_bf, unsigned short* __restrict__ Wqk_t,
    unsigned short* __restrict__ Wv_t, unsigned short* __restrict__ Wp_t)
{
    __shared__ unsigned short T[64 * 72];
    const int bid = blockIdx.x, tid = threadIdx.x;
    if (bid < 64) {
        const float* src; unsigned short* dst; int N_, kt, nt;
        if (bid < 32)      { src = Wqk; dst = Wqk_t; N_ = 512; kt = bid & 3; nt = bid >> 2; }
        else if (bid < 48) { int t = bid - 32; src = Wv;  dst = Wv_t; N_ = 256; kt = t & 3; nt = t >> 2; }
        else               { int t = bid - 48; src = Wpj; dst = Wp_t; N_ = 256; kt = t & 3; nt = t >> 2; }
        const int kr = tid >> 2, seg = tid & 3;
        #pragma unroll
        for (int u = 0; u < 4; ++u) {
            float4 v = *(const float4*)(src + (kt * 64 + kr) * N_ + nt * 64 + seg * 16 + u * 4);
            T[(seg * 16 + u * 4 + 0) * 72 + kr] = f2bf(v.x);
            T[(seg * 16 + u * 4 + 1) * 72 + kr] = f2bf(v.y);
            T[(seg * 16 + u * 4 + 2) * 72 + kr] = f2bf(v.z);
            T[(seg * 16 + u * 4 + 3) * 72 + kr] = f2bf(v.w);
        }
        __syncthreads();
        const int n = tid >> 2, s2 = tid & 3;
        uint4 a = *(uint4*)&T[n * 72 + s2 * 16];
        uint4 b2 = *(uint4*)&T[n * 72 + s2 * 16 + 8];
        *(uint4*)(dst + (nt * 64 + n) * 256 + kt * 64 + s2 * 16) = a;
        *(uint4*)(dst + (nt * 64 + n) * 256 + kt * 64 + s2 * 16 + 8) = b2;
    } else {
        const int cb2 = bid - 64;
        const float4* xs = (const float4*)x + (size_t)cb2 * 8192;
        uint2* xd = (uint2*)x_bf + (size_t)cb2 * 8192;
        for (int i = tid; i < 8192; i += 256) {
            float4 v = xs[i];
            uint2 o;
            o.x = (unsigned)f2bf(v.x) | ((unsigned)f2bf(v.y) << 16);
            o.y = (unsigned)f2bf(v.z) | ((unsigned)f2bf(v.w) << 16);
            xd[i] = o;
        }
    }
}

// ---------------- kernel 2: QKV projection GEMM (M=4096, N=768, K=256), gload_lds + XOR swizzle ----------------
__global__ __launch_bounds__(256) void k_qkv(
    const unsigned short* __restrict__ x_bf,
    const unsigned short* __restrict__ Wqk_t,
    const unsigned short* __restrict__ Wv_t,
    unsigned short* __restrict__ q_ws, unsigned short* __restrict__ k_ws,
    unsigned short* __restrict__ v_ws)
{
    __shared__ unsigned short Al[64 * 64];   // [r][64], 128B rows, 16B-unit XOR swizzle c^(r&7)
    __shared__ unsigned short Bl[64 * 64];
    const int tid = threadIdx.x;
    const int n0 = blockIdx.x * 64;
    const int row0 = blockIdx.y * 64;
    const int w = tid >> 6, lane = tid & 63;
    const int lhi = lane >> 4, llo = lane & 15;
    const unsigned short* Bsrc = (n0 < 512) ? (Wqk_t + n0 * 256) : (Wv_t + (n0 - 512) * 256);

    const int sr = lane >> 3, sc = lane & 7;          // staging: r-sub, col-unit
    const int scx = sc ^ (sr & 7);                    // pre-swizzled source column unit

    f32x4_t acc[4] = {};
    for (int kc = 0; kc < 4; ++kc) {
        #pragma unroll
        for (int s = 0; s < 2; ++s) {
            int chunk = w * 2 + s;                    // 8 chunks of 1KB (8 rows each)
            int r = chunk * 8 + sr;
            stage16(x_bf + (row0 + r) * 256 + kc * 64 + scx * 8, &Al[chunk * 512], lane);
            stage16(Bsrc + r * 256 + kc * 64 + scx * 8, &Bl[chunk * 512], lane);
        }
        __syncthreads();
        #pragma unroll
        for (int ks = 0; ks < 2; ++ks) {
            int ua = ((ks * 4 + lhi) ^ (llo & 7)) * 8;
            bf16x8_t a = *(const bf16x8_t*)(&Al[(w * 16 + llo) * 64 + ua]);
            #pragma unroll
            for (int nt = 0; nt < 4; ++nt) {
                bf16x8_t b = *(const bf16x8_t*)(&Bl[(nt * 16 + llo) * 64 + ua]);
                acc[nt] = __builtin_amdgcn_mfma_f32_16x16x32_bf16(a, b, acc[nt], 0, 0, 0);
            }
        }
        __syncthreads();
    }
    constexpr float QSC = (float)(1.4426950408889634 / 5.656854249492380195206754896838);
    #pragma unroll
    for (int nt = 0; nt < 4; ++nt) {
        int ng = n0 + nt * 16 + llo;
        #pragma unroll
        for (int r = 0; r < 4; ++r) {
            int ig = row0 + w * 16 + lhi * 4 + r;
            float val = acc[nt][r];
            int b = ig >> 10, i = ig & 1023;
            if (ng < 256) {
                int h = ng >> 5, d = ng & 31;
                q_ws[((b * 8 + h) * 1024 + i) * 32 + d] = f2bf(val * QSC);
            } else if (ng < 512) {
                int c = ng - 256, h = c >> 5, d = c & 31;
                k_ws[((b * 8 + h) * 1024 + i) * 32 + d] = f2bf(val);
            } else {
                int c = ng - 512, h = c >> 5, d = c & 31;
                v_ws[((b * 8 + h) * 1024 + i) * 32 + d] = f2bf(val);
            }
        }
    }
}

// ---------------- kernel 3: fused dual-softmax attention (swapped QK^T, LDS j-tables) ----------------
// grid: 1024 blocks = 32 bh x 16 it x 2 jh (XCD-swizzled), 256 threads (4 waves x 16 i-rows)
__global__ __launch_bounds__(256) void k_attn(
    const unsigned short* __restrict__ q_ws,
    const unsigned short* __restrict__ k_ws,
    const unsigned short* __restrict__ v_ws,
    const float* __restrict__ coords,
    const float* __restrict__ W_pos,
    const float* __restrict__ b_pos,
    float* __restrict__ part)
{
    __shared__ unsigned short Kl[64 * 32];   // K tile [j][d] 64B rows, 16B-unit swizzle u^(j&3)
    __shared__ unsigned short Vt[32 * 72];   // V^T tile [d][j], 144B rows
    __shared__ unsigned short Wp[64 * 72];   // exp(patch logit) [i][j]
    __shared__ unsigned short Wq[64 * 72];   // exp(pos logit)   [i][j]
    __shared__ float4 XYZS[512];             // per-j {x,y,z,|p|^2} for this j-half
    __shared__ float  AJ[512];               // per-j log2e*(w·p_j + b_pos)

    const int tid = threadIdx.x;
    const int bid = blockIdx.x;
    const int xcd = bid & 7, idx = bid >> 3;
    const int bh = xcd * 4 + (idx >> 5);
    const int rem = idx & 31;
    const int it = rem >> 1;
    const int jh = rem & 1;
    const int b = bh >> 3, h = bh & 7;

    const int w = tid >> 6, lane = tid & 63;
    const int lhi = lane >> 4, llo = lane & 15;

    const float wxl = W_pos[0 * 8 + h] * LOG2E;
    const float wyl = W_pos[1 * 8 + h] * LOG2E;
    const float wzl = W_pos[2 * 8 + h] * LOG2E;
    const float wdl = W_pos[3 * 8 + h] * LOG2E;
    const float bpl = b_pos[h] * LOG2E;

    const int i_base = it * 64 + w * 16;
    // qf used as B-frag of swapped QK^T: lane llo = i, elems d = lhi*8+e
    bf16x8_t qf = *(const bf16x8_t*)(q_ws + (bh * 1024 + i_base + llo) * 32 + lhi * 8);

    const float* cb_ = coords + b * 3072;
    // i-side per-lane constants
    const int ig = i_base + llo;
    float xi = cb_[ig * 3 + 0], yi = cb_[ig * 3 + 1], zi = cb_[ig * 3 + 2];
    float si = fmaf(xi, xi, fmaf(yi, yi, zi * zi));
    float cil = fmaf(wzl, zi, fmaf(wyl, yi, wxl * xi));

    // stage per-j tables for this j-half
    for (int jl = tid; jl < 512; jl += 256) {
        int jg = jh * 512 + jl;
        float xj = cb_[jg * 3 + 0], yj = cb_[jg * 3 + 1], zj = cb_[jg * 3 + 2];
        XYZS[jl] = make_float4(xj, yj, zj, fmaf(xj, xj, fmaf(yj, yj, zj * zj)));
        AJ[jl] = fmaf(wzl, zj, fmaf(wyl, yj, wxl * xj)) + bpl;
    }

    bf16x8_t ones;
    #pragma unroll
    for (int e = 0; e < 8; ++e) ones[e] = (short)0x3F80;   // bf16 1.0

    f32x4_t accP[2] = {}, accQ[2] = {};
    f32x4_t accLp = {}, accLq = {};

    const int ksr = lane >> 2, ksc = lane & 3;          // Kl staging coords
    const int kscx = ksc ^ (ksr & 3);
    __syncthreads();   // tables ready

    for (int t = 0; t < 8; ++t) {
        const int j0 = jh * 512 + t * 64;               // global j tile base
        const int jlb0 = t * 64;                        // local (table) base
        // stage K via gload_lds (swizzled source), V^T via in-LDS transpose
        {
            int r = w * 16 + ksr;
            stage16(k_ws + (bh * 1024 + j0 + r) * 32 + kscx * 8, &Kl[w * 512], lane);
            uint4 vv = *(const uint4*)(v_ws + (bh * 1024 + j0 + lane) * 32 + w * 8);
            const unsigned short* pv = (const unsigned short*)&vv;
            #pragma unroll
            for (int e = 0; e < 8; ++e) Vt[(w * 8 + e) * 72 + lane] = pv[e];
        }
        __syncthreads();

        // ---- swapped QK^T: sv = mfma(K,Q) -> lane: i=llo, j=jq*16+lhi*4+r ----
        #pragma unroll
        for (int jq = 0; jq < 4; ++jq) {
            int krow = jq * 16 + llo;
            bf16x8_t kf = *(const bf16x8_t*)(&Kl[krow * 32 + ((lhi ^ (krow & 3)) * 8)]);
            f32x4_t zero = {};
            f32x4_t sv = __builtin_amdgcn_mfma_f32_16x16x32_bf16(kf, qf, zero, 0, 0, 0);
            int jlb = jlb0 + jq * 16 + lhi * 4;
            float ep[4], eq[4];
            #pragma unroll
            for (int r = 0; r < 4; ++r) {
                float4 cj = XYZS[jlb + r];
                float aj = AJ[jlb + r];
                float dot = fmaf(cj.x, xi, fmaf(cj.y, yi, cj.z * zi));
                float d2 = fmaf(-2.0f, dot, si + cj.w);
                float dist = SQRTF_(d2);
                float spos = fmaf(wdl, dist, aj - cil);
                ep[r] = EXP2F_(sv[r]);
                eq[r] = EXP2F_(spos);
            }
            uint2 wpP, wpQ;
            wpP.x = pk2(ep[0], ep[1]); wpP.y = pk2(ep[2], ep[3]);
            wpQ.x = pk2(eq[0], eq[1]); wpQ.y = pk2(eq[2], eq[3]);
            int off = (w * 16 + llo) * 72 + jq * 16 + lhi * 4;
            *(uint2*)(&Wp[off]) = wpP;
            *(uint2*)(&Wq[off]) = wpQ;
        }

        // ---- PV MFMA + denominator rows via ones-vector MFMA (same-wave LDS dep) ----
        #pragma unroll
        for (int jb = 0; jb < 2; ++jb) {
            bf16x8_t bP = *(const bf16x8_t*)(&Wp[(w * 16 + llo) * 72 + jb * 32 + lhi * 8]);
            bf16x8_t bQ = *(const bf16x8_t*)(&Wq[(w * 16 + llo) * 72 + jb * 32 + lhi * 8]);
            accLp = __builtin_amdgcn_mfma_f32_16x16x32_bf16(ones, bP, accLp, 0, 0, 0);
            accLq = __builtin_amdgcn_mfma_f32_16x16x32_bf16(ones, bQ, accLq, 0, 0, 0);
            #pragma unroll
            for (int dt = 0; dt < 2; ++dt) {
                bf16x8_t af = *(const bf16x8_t*)(&Vt[(dt * 16 + llo) * 72 + jb * 32 + lhi * 8]);
                accP[dt] = __builtin_amdgcn_mfma_f32_16x16x32_bf16(af, bP, accP[dt], 0, 0, 0);
                accQ[dt] = __builtin_amdgcn_mfma_f32_16x16x32_bf16(af, bQ, accQ[dt], 0, 0, 0);
            }
        }
        __syncthreads();
    }

    float* pb = part + (size_t)((bh * 16 + it) * 2 + jh) * 4224;
    #pragma unroll
    for (int dt = 0; dt < 2; ++dt) {
        #pragma unroll
        for (int r = 0; r < 4; ++r) {
            int d = dt * 16 + lhi * 4 + r;
            pb[d * 64 + w * 16 + llo] = accP[dt][r];
            pb[2048 + d * 64 + w * 16 + llo] = accQ[dt][r];
        }
    }
    if (lane < 16) {
        pb[4096 + w * 16 + lane] = accLp[0];
        pb[4160 + w * 16 + lane] = accLq[0];
    }
}

// ---------------- kernel 4: combine j-halves, normalize, gate -> o_ws bf16 ----------------
__global__ __launch_bounds__(256) void k_comb(
    const float* __restrict__ part, const float* __restrict__ gating,
    unsigned short* __restrict__ o_ws)
{
    const int bid = blockIdx.x;              // 512 = bh*16 + it
    const int bh = bid >> 4, it = bid & 15;
    const int b = bh >> 3, h = bh & 7;
    const int tid = threadIdx.x, w = tid >> 6, i = tid & 63;
    const float* p0 = part + (size_t)(bid * 2) * 4224;
    const float* p1 = p0 + 4224;
    float sig = 1.0f / (1.0f + __expf(-gating[h]));
    float Lp = p0[4096 + i] + p1[4096 + i];
    float Lq = p0[4160 + i] + p1[4160 + i];
    float ca = (1.0f - sig) / Lp, cb2 = sig / Lq;
    unsigned short ob[8];
    #pragma unroll
    for (int e = 0; e < 8; ++e) {
        int d = w * 8 + e;
        float Op = p0[d * 64 + i] + p1[d * 64 + i];
        float Oq = p0[2048 + d * 64 + i] + p1[2048 + d * 64 + i];
        ob[e] = f2bf(ca * Op + cb2 * Oq);
    }
    *(uint4*)(o_ws + ((size_t)(b * 1024 + it * 64 + i)) * 256 + h * 32 + w * 8) = *(uint4*)ob;
}

// ---------------- kernel 5: output projection GEMM (M=4096, N=256, K=256) + bias ----------------
__global__ __launch_bounds__(256) void k_proj(
    const unsigned short* __restrict__ A,
    const unsigned short* __restrict__ Bt,
    const float* __restrict__ bias,
    float* __restrict__ out)
{
    __shared__ unsigned short Al[64 * 64];
    __shared__ unsigned short Bl[64 * 64];
    const int tid = threadIdx.x;
    const int n0 = blockIdx.x * 64;
    const int row0 = blockIdx.y * 64;
    const int w = tid >> 6, lane = tid & 63;
    const int lhi = lane >> 4, llo = lane & 15;
    const int sr = lane >> 3, sc = lane & 7;
    const int scx = sc ^ (sr & 7);

    f32x4_t acc[4] = {};
    for (int kc = 0; kc < 4; ++kc) {
        #pragma unroll
        for (int s = 0; s < 2; ++s) {
            int chunk = w * 2 + s;
            int r = chunk * 8 + sr;
            stage16(A + (row0 + r) * 256 + kc * 64 + scx * 8, &Al[chunk * 512], lane);
            stage16(Bt + (n0 + r) * 256 + kc * 64 + scx * 8, &Bl[chunk * 512], lane);
        }
        __syncthreads();
        #pragma unroll
        for (int ks = 0; ks < 2; ++ks) {
            int ua = ((ks * 4 + lhi) ^ (llo & 7)) * 8;
            bf16x8_t a = *(const bf16x8_t*)(&Al[(w * 16 + llo) * 64 + ua]);
            #pragma unroll
            for (int nt = 0; nt < 4; ++nt) {
                bf16x8_t b = *(const bf16x8_t*)(&Bl[(nt * 16 + llo) * 64 + ua]);
                acc[nt] = __builtin_amdgcn_mfma_f32_16x16x32_bf16(a, b, acc[nt], 0, 0, 0);
            }
        }
        __syncthreads();
    }
    #pragma unroll
    for (int nt = 0; nt < 4; ++nt) {
        int ng = n0 + nt * 16 + llo;
        float bv = bias[ng];
        #pragma unroll
        for (int r = 0; r < 4; ++r) {
            int ig = row0 + w * 16 + lhi * 4 + r;
            out[ig * 256 + ng] = acc[nt][r] + bv;
        }
    }
}

// ---------------- launcher ----------------
extern "C" void kernel_launch(void* const* d_in, const int* in_sizes, int n_in,
                              void* d_out, int out_size, void* d_ws, size_t ws_size,
                              hipStream_t stream)
{
    const float* x    = (const float*)d_in[0];
    const float* vc   = (const float*)d_in[1];
    const float* Wqk  = (const float*)d_in[2];
    const float* Wv   = (const float*)d_in[3];
    const float* Wpj  = (const float*)d_in[4];
    const float* bpj  = (const float*)d_in[5];
    const float* Wpos = (const float*)d_in[6];
    const float* bpos = (const float*)d_in[7];
    const float* gat  = (const float*)d_in[8];
    float* out = (float*)d_out;

    char* ws = (char*)d_ws;
    unsigned short* x_bf  = (unsigned short*)(ws + 0);          // 2 MB
    unsigned short* Wqk_t = (unsigned short*)(ws + 2097152);    // 256 KB
    unsigned short* Wv_t  = (unsigned short*)(ws + 2359296);    // 128 KB
    unsigned short* Wp_t  = (unsigned short*)(ws + 2490368);    // 128 KB
    unsigned short* q_ws  = (unsigned short*)(ws + 2621440);    // 2 MB
    unsigned short* k_ws  = (unsigned short*)(ws + 4718592);    // 2 MB
    unsigned short* v_ws  = (unsigned short*)(ws + 6815744);    // 2 MB
    unsigned short* o_ws  = (unsigned short*)(ws + 8912896);    // 2 MB
    float*          partf = (float*)(ws + 11010048);            // 16.5 MB partials

    hipLaunchKernelGGL(k_convert, dim3(96), dim3(256), 0, stream,
                       x, Wqk, Wv, Wpj, x_bf, Wqk_t, Wv_t, Wp_t);
    hipLaunchKernelGGL(k_qkv, dim3(12, 64), dim3(256), 0, stream,
                       x_bf, Wqk_t, Wv_t, q_ws, k_ws, v_ws);
    hipLaunchKernelGGL(k_attn, dim3(1024), dim3(256), 0, stream,
                       q_ws, k_ws, v_ws, vc, Wpos, bpos, partf);
    hipLaunchKernelGGL(k_comb, dim3(512), dim3(256), 0, stream,
                       partf, gat, o_ws);
    hipLaunchKernelGGL(k_proj, dim3(4, 64), dim3(256), 0, stream,
                       o_ws, Wp_t, bpj, out);
}

// Round 4
// 123.680 us; speedup vs baseline: 1.1598x; 1.0161x over previous
//
#include <hip/hip_runtime.h>
#include <hip/hip_bf16.h>

// ---------------- problem constants ----------------
// B=4, N=1024, C=256, H=8, HD=32, SCALE=HD^-0.5
#define LOG2E 1.4426950408889634f

typedef __attribute__((ext_vector_type(8))) short bf16x8_t;   // 8 bf16 (4 VGPRs) — mfma A/B frag
typedef __attribute__((ext_vector_type(4))) float f32x4_t;    // mfma C/D frag

#if __has_builtin(__builtin_amdgcn_exp2f)
#define EXP2F_(x) __builtin_amdgcn_exp2f(x)
#else
__device__ __forceinline__ float EXP2F_(float x) {
    float r; asm volatile("v_exp_f32 %0, %1\ns_nop 1" : "=v"(r) : "v"(x)); return r;
}
#endif
#if __has_builtin(__builtin_amdgcn_sqrtf)
#define SQRTF_(x) __builtin_amdgcn_sqrtf(x)
#else
__device__ __forceinline__ float SQRTF_(float x) {
    float r; asm volatile("v_sqrt_f32 %0, %1\ns_nop 1" : "=v"(r) : "v"(x)); return r;
}
#endif

__device__ __forceinline__ unsigned short f2bf(float f) {
    unsigned u = __float_as_uint(f);
    u += 0x7fffu + ((u >> 16) & 1u);      // RNE
    return (unsigned short)(u >> 16);
}

// pack 2 f32 -> u32 of 2 bf16 (lo = first) — compiles to v_cvt_pk_bf16_f32
__device__ __forceinline__ unsigned pk2(float lo, float hi) {
    union { __hip_bfloat162 h2; unsigned u; } cvt;
    cvt.h2 = __float22bfloat162_rn(make_float2(lo, hi));
    return cvt.u;
}

// global(per-lane) -> LDS(wave-uniform base + lane*16) direct 16B copy
__device__ __forceinline__ void stage16(const unsigned short* g, unsigned short* l, int lane) {
#if __has_builtin(__builtin_amdgcn_global_load_lds)
    __builtin_amdgcn_global_load_lds((const __attribute__((address_space(1))) void*)g,
                                     (__attribute__((address_space(3))) void*)l, 16, 0, 0);
#else
    *(uint4*)((char*)l + lane * 16) = *(const uint4*)g;
#endif
}

// ---------------- kernel 1: weight transposes f32->bf16 (via LDS, coalesced out) ----------------
__global__ __launch_bounds__(256) void k_convert(
    const float* __restrict__ Wqk, const float* __restrict__ Wv,
    const float* __restrict__ Wpj,
    unsigned short* __restrict__ Wqk_t, unsigned short* __restrict__ Wv_t,
    unsigned short* __restrict__ Wp_t)
{
    __shared__ unsigned short T[64 * 72];
    const int bid = blockIdx.x, tid = threadIdx.x;
    const float* src; unsigned short* dst; int N_, kt, nt;
    if (bid < 32)      { src = Wqk; dst = Wqk_t; N_ = 512; kt = bid & 3; nt = bid >> 2; }
    else if (bid < 48) { int t = bid - 32; src = Wv;  dst = Wv_t; N_ = 256; kt = t & 3; nt = t >> 2; }
    else               { int t = bid - 48; src = Wpj; dst = Wp_t; N_ = 256; kt = t & 3; nt = t >> 2; }
    const int kr = tid >> 2, seg = tid & 3;
    #pragma unroll
    for (int u = 0; u < 4; ++u) {
        float4 v = *(const float4*)(src + (kt * 64 + kr) * N_ + nt * 64 + seg * 16 + u * 4);
        T[(seg * 16 + u * 4 + 0) * 72 + kr] = f2bf(v.x);
        T[(seg * 16 + u * 4 + 1) * 72 + kr] = f2bf(v.y);
        T[(seg * 16 + u * 4 + 2) * 72 + kr] = f2bf(v.z);
        T[(seg * 16 + u * 4 + 3) * 72 + kr] = f2bf(v.w);
    }
    __syncthreads();
    const int n = tid >> 2, s2 = tid & 3;
    uint4 a = *(uint4*)&T[n * 72 + s2 * 16];
    uint4 b2 = *(uint4*)&T[n * 72 + s2 * 16 + 8];
    *(uint4*)(dst + (nt * 64 + n) * 256 + kt * 64 + s2 * 16) = a;
    *(uint4*)(dst + (nt * 64 + n) * 256 + kt * 64 + s2 * 16 + 8) = b2;
}

// ---------------- kernel 2: QKV projection GEMM (M=4096, N=768, K=256) ----------------
// A staged from f32 x with in-flight cvt; B via gload_lds. q pre-scaled by SCALE*log2e.
__global__ __launch_bounds__(256) void k_qkv(
    const float* __restrict__ x,
    const unsigned short* __restrict__ Wqk_t,
    const unsigned short* __restrict__ Wv_t,
    unsigned short* __restrict__ q_ws, unsigned short* __restrict__ k_ws,
    unsigned short* __restrict__ v_ws)
{
    __shared__ unsigned short Al[64 * 64];   // [r][64], 128B rows, 16B-unit XOR swizzle u^(r&7)
    __shared__ unsigned short Bl[64 * 64];
    const int tid = threadIdx.x;
    const int n0 = blockIdx.x * 64;
    const int row0 = blockIdx.y * 64;
    const int w = tid >> 6, lane = tid & 63;
    const int lhi = lane >> 4, llo = lane & 15;
    const unsigned short* Bsrc = (n0 < 512) ? (Wqk_t + n0 * 256) : (Wv_t + (n0 - 512) * 256);

    const int sr = lane >> 3, sc = lane & 7;
    const int scx = sc ^ sr;                           // pre-swizzled source column unit

    f32x4_t acc[4] = {};
    for (int kc = 0; kc < 4; ++kc) {
        #pragma unroll
        for (int s = 0; s < 2; ++s) {
            int chunk = w * 2 + s;
            int r = chunk * 8 + sr;
            // A: f32 load + cvt + swizzled ds_write (content = logical unit scx at phys slot sc)
            const float* ax = x + (row0 + r) * 256 + kc * 64 + scx * 8;
            float4 a0 = *(const float4*)ax, a1 = *(const float4*)(ax + 4);
            uint4 pk;
            pk.x = pk2(a0.x, a0.y); pk.y = pk2(a0.z, a0.w);
            pk.z = pk2(a1.x, a1.y); pk.w = pk2(a1.z, a1.w);
            *(uint4*)(&Al[r * 64 + sc * 8]) = pk;
            // B: direct DMA, pre-swizzled source
            stage16(Bsrc + r * 256 + kc * 64 + scx * 8, &Bl[chunk * 512], lane);
        }
        __syncthreads();
        #pragma unroll
        for (int ks = 0; ks < 2; ++ks) {
            int ua = ((ks * 4 + lhi) ^ (llo & 7)) * 8;
            bf16x8_t a = *(const bf16x8_t*)(&Al[(w * 16 + llo) * 64 + ua]);
            #pragma unroll
            for (int nt = 0; nt < 4; ++nt) {
                bf16x8_t b = *(const bf16x8_t*)(&Bl[(nt * 16 + llo) * 64 + ua]);
                acc[nt] = __builtin_amdgcn_mfma_f32_16x16x32_bf16(a, b, acc[nt], 0, 0, 0);
            }
        }
        __syncthreads();
    }
    constexpr float QSC = (float)(1.4426950408889634 / 5.656854249492380195206754896838);
    #pragma unroll
    for (int nt = 0; nt < 4; ++nt) {
        int ng = n0 + nt * 16 + llo;
        #pragma unroll
        for (int r = 0; r < 4; ++r) {
            int ig = row0 + w * 16 + lhi * 4 + r;
            float val = acc[nt][r];
            int b = ig >> 10, i = ig & 1023;
            if (ng < 256) {
                int h = ng >> 5, d = ng & 31;
                q_ws[((b * 8 + h) * 1024 + i) * 32 + d] = f2bf(val * QSC);
            } else if (ng < 512) {
                int c = ng - 256, h = c >> 5, d = c & 31;
                k_ws[((b * 8 + h) * 1024 + i) * 32 + d] = f2bf(val);
            } else {
                int c = ng - 512, h = c >> 5, d = c & 31;
                v_ws[((b * 8 + h) * 1024 + i) * 32 + d] = f2bf(val);
            }
        }
    }
}

// ---------------- kernel 3: fused dual-softmax attention, in-block J-split ----------------
// grid: 512 blocks = 32 bh x 16 it (XCD-swizzled); 512 threads = 8 waves (4 wi x 2 wj)
// wave (wi,wj): 16 i-rows (wi), j-half (wj). Epilogue: LDS combine + gate + normalize -> o_ws.
__global__ __launch_bounds__(512, 6) void k_attn(
    const unsigned short* __restrict__ q_ws,
    const unsigned short* __restrict__ k_ws,
    const unsigned short* __restrict__ v_ws,
    const float* __restrict__ coords,
    const float* __restrict__ W_pos,
    const float* __restrict__ b_pos,
    const float* __restrict__ gating,
    unsigned short* __restrict__ o_ws)
{
    __shared__ unsigned short Kl[2 * 64 * 32];   // [wj][j][d], 64B rows (naturally bank-spread)
    __shared__ unsigned short Vt[2 * 32 * 64];   // [wj][d][j], 128B rows, unit swizzle u^(d&7)
    __shared__ unsigned short Wp[2 * 64 * 64];   // [wj][i][j] exp(patch), unit swizzle u^(i&7)
    __shared__ unsigned short Wq[2 * 64 * 64];   // [wj][i][j] exp(pos)
    __shared__ float4 TX[128];                   // per-tile {x,y,z,|p|^2}, both halves
    __shared__ float  TA[128];                   // per-tile log2e*(w.p_j)+b

    const int tid = threadIdx.x;
    const int bid = blockIdx.x;
    const int xcd = bid & 7, s = bid >> 3;
    const int bh = xcd * 4 + (s >> 4);
    const int it = s & 15;
    const int b = bh >> 3, h = bh & 7;

    const int w = tid >> 6, lane = tid & 63;
    const int wi = w & 3, wj = w >> 2;
    const int lhi = lane >> 4, llo = lane & 15;

    const float wxl = W_pos[0 * 8 + h] * LOG2E;
    const float wyl = W_pos[1 * 8 + h] * LOG2E;
    const float wzl = W_pos[2 * 8 + h] * LOG2E;
    const float wdl = W_pos[3 * 8 + h] * LOG2E;
    const float bpl = b_pos[h] * LOG2E;

    const int i_base = it * 64 + wi * 16;
    // qf = B-frag of swapped QK^T: lane llo = i, elems d = lhi*8+e
    bf16x8_t qf = *(const bf16x8_t*)(q_ws + (bh * 1024 + i_base + llo) * 32 + lhi * 8);

    const float* cb_ = coords + b * 3072;
    const int ig = i_base + llo;
    float xi = cb_[ig * 3 + 0], yi = cb_[ig * 3 + 1], zi = cb_[ig * 3 + 2];
    float si = fmaf(xi, xi, fmaf(yi, yi, zi * zi));
    float cil = fmaf(wzl, zi, fmaf(wyl, yi, wxl * xi));

    bf16x8_t ones;
    #pragma unroll
    for (int e = 0; e < 8; ++e) ones[e] = (short)0x3F80;   // bf16 1.0

    f32x4_t accP[2] = {}, accQ[2] = {};
    f32x4_t accLp = {}, accLq = {};

    const int jhbase = wj * 512;
    const int wc = w & 3;                         // staging d/j chunk (= wi)

    for (int t = 0; t < 8; ++t) {
        const int j0s = (w >> 2) * 512 + t * 64;  // this wave's staging j-base
        // --- stage: K via gload_lds (1KB/wave), V via reg->LDS transpose, tables (tid<128) ---
        stage16(k_ws + (bh * 1024 + j0s + wc * 16 + (lane >> 2)) * 32 + (lane & 3) * 8,
                &Kl[(w >> 2) * 2048 + wc * 512], lane);
        {
            uint4 vv = *(const uint4*)(v_ws + (bh * 1024 + j0s + lane) * 32 + wc * 8);
            const unsigned short* pv = (const unsigned short*)&vv;
            #pragma unroll
            for (int e = 0; e < 8; ++e)
                Vt[((w >> 2) * 32 + wc * 8 + e) * 64 + (((lane >> 3) ^ e) * 8) + (lane & 7)] = pv[e];
        }
        if (tid < 128) {
            int half = tid >> 6, jl = tid & 63;
            int jg = half * 512 + t * 64 + jl;
            float xj = cb_[jg * 3 + 0], yj = cb_[jg * 3 + 1], zj = cb_[jg * 3 + 2];
            TX[half * 64 + jl] = make_float4(xj, yj, zj, fmaf(xj, xj, fmaf(yj, yj, zj * zj)));
            TA[half * 64 + jl] = fmaf(wzl, zj, fmaf(wyl, yj, wxl * xj)) + bpl;
        }
        __syncthreads();

        // --- swapped QK^T: sv = mfma(K,Q) -> lane: i=llo, j=jq*16+lhi*4+r ---
        #pragma unroll
        for (int jq = 0; jq < 4; ++jq) {
            bf16x8_t kf = *(const bf16x8_t*)(&Kl[wj * 2048 + (jq * 16 + llo) * 32 + lhi * 8]);
            f32x4_t zero = {};
            f32x4_t sv = __builtin_amdgcn_mfma_f32_16x16x32_bf16(kf, qf, zero, 0, 0, 0);
            int jlb = wj * 64 + jq * 16 + lhi * 4;
            float ep[4], eq[4];
            #pragma unroll
            for (int r = 0; r < 4; ++r) {
                float4 cj = TX[jlb + r];
                float aj = TA[jlb + r];
                float dot = fmaf(cj.x, xi, fmaf(cj.y, yi, cj.z * zi));
                float d2 = fmaf(-2.0f, dot, si + cj.w);
                float dist = SQRTF_(d2);
                float spos = fmaf(wdl, dist, aj - cil);
                ep[r] = EXP2F_(sv[r]);
                eq[r] = EXP2F_(spos);
            }
            // row i = wi*16+llo; uint2 at unit (jq*2+(lhi>>1)) ^ (llo&7), sub (lhi&1)*8B
            int row = wj * 64 + wi * 16 + llo;
            int off = row * 64 + (((jq * 2 + (lhi >> 1)) ^ (llo & 7)) * 8) + (lhi & 1) * 4;
            uint2 uP, uQ;
            uP.x = pk2(ep[0], ep[1]); uP.y = pk2(ep[2], ep[3]);
            uQ.x = pk2(eq[0], eq[1]); uQ.y = pk2(eq[2], eq[3]);
            *(uint2*)(&Wp[off]) = uP;
            *(uint2*)(&Wq[off]) = uQ;
        }

        // --- PV + L-rows via ones-MFMA (same-wave LDS dep, no barrier) ---
        #pragma unroll
        for (int jb = 0; jb < 2; ++jb) {
            int uu = ((jb * 4 + lhi) ^ (llo & 7)) * 8;
            bf16x8_t bP = *(const bf16x8_t*)(&Wp[(wj * 64 + wi * 16 + llo) * 64 + uu]);
            bf16x8_t bQ = *(const bf16x8_t*)(&Wq[(wj * 64 + wi * 16 + llo) * 64 + uu]);
            accLp = __builtin_amdgcn_mfma_f32_16x16x32_bf16(ones, bP, accLp, 0, 0, 0);
            accLq = __builtin_amdgcn_mfma_f32_16x16x32_bf16(ones, bQ, accLq, 0, 0, 0);
            #pragma unroll
            for (int dt = 0; dt < 2; ++dt) {
                bf16x8_t af = *(const bf16x8_t*)(&Vt[(wj * 32 + dt * 16 + llo) * 64 + uu]);
                accP[dt] = __builtin_amdgcn_mfma_f32_16x16x32_bf16(af, bP, accP[dt], 0, 0, 0);
                accQ[dt] = __builtin_amdgcn_mfma_f32_16x16x32_bf16(af, bQ, accQ[dt], 0, 0, 0);
            }
        }
        __syncthreads();
    }

    // --- epilogue: cross-half combine in LDS (reuse Wp/Wq), gate+normalize, write o_ws ---
    float* red = (float*)Wp;     // 4096 f32: [wi*64+lane][16]
    float* LPQ = (float*)Wq;     // [0..63] Lp, [64..127] Lq
    if (wj == 1) {
        float* pr = red + (wi * 64 + lane) * 16;
        *(f32x4_t*)(pr + 0) = accP[0]; *(f32x4_t*)(pr + 4)  = accP[1];
        *(f32x4_t*)(pr + 8) = accQ[0]; *(f32x4_t*)(pr + 12) = accQ[1];
        if (lhi == 0) { LPQ[wi * 16 + llo] = accLp[0]; LPQ[64 + wi * 16 + llo] = accLq[0]; }
    }
    __syncthreads();
    if (wj == 0) {
        const float* pr = red + (wi * 64 + lane) * 16;
        float Lp = accLp[0] + LPQ[wi * 16 + llo];
        float Lq = accLq[0] + LPQ[64 + wi * 16 + llo];
        float sig = 1.0f / (1.0f + __expf(-gating[h]));
        float ca = (1.0f - sig) / Lp, cb2 = sig / Lq;
        int rowg = b * 1024 + it * 64 + wi * 16 + llo;
        #pragma unroll
        for (int dt = 0; dt < 2; ++dt) {
            float o0 = ca * (accP[dt][0] + pr[dt * 4 + 0]) + cb2 * (accQ[dt][0] + pr[8 + dt * 4 + 0]);
            float o1 = ca * (accP[dt][1] + pr[dt * 4 + 1]) + cb2 * (accQ[dt][1] + pr[8 + dt * 4 + 1]);
            float o2 = ca * (accP[dt][2] + pr[dt * 4 + 2]) + cb2 * (accQ[dt][2] + pr[8 + dt * 4 + 2]);
            float o3 = ca * (accP[dt][3] + pr[dt * 4 + 3]) + cb2 * (accQ[dt][3] + pr[8 + dt * 4 + 3]);
            uint2 uu;
            uu.x = pk2(o0, o1); uu.y = pk2(o2, o3);
            *(uint2*)(o_ws + (size_t)rowg * 256 + h * 32 + dt * 16 + lhi * 4) = uu;
        }
    }
}

// ---------------- kernel 4: output projection GEMM (M=4096, N=256, K=256) + bias ----------------
__global__ __launch_bounds__(256) void k_proj(
    const unsigned short* __restrict__ A,
    const unsigned short* __restrict__ Bt,
    const float* __restrict__ bias,
    float* __restrict__ out)
{
    __shared__ unsigned short Al[64 * 64];
    __shared__ unsigned short Bl[64 * 64];
    const int tid = threadIdx.x;
    const int n0 = blockIdx.x * 64;
    const int row0 = blockIdx.y * 64;
    const int w = tid >> 6, lane = tid & 63;
    const int lhi = lane >> 4, llo = lane & 15;
    const int sr = lane >> 3, sc = lane & 7;
    const int scx = sc ^ sr;

    f32x4_t acc[4] = {};
    for (int kc = 0; kc < 4; ++kc) {
        #pragma unroll
        for (int s = 0; s < 2; ++s) {
            int chunk = w * 2 + s;
            int r = chunk * 8 + sr;
            stage16(A + (row0 + r) * 256 + kc * 64 + scx * 8, &Al[chunk * 512], lane);
            stage16(Bt + (n0 + r) * 256 + kc * 64 + scx * 8, &Bl[chunk * 512], lane);
        }
        __syncthreads();
        #pragma unroll
        for (int ks = 0; ks < 2; ++ks) {
            int ua = ((ks * 4 + lhi) ^ (llo & 7)) * 8;
            bf16x8_t a = *(const bf16x8_t*)(&Al[(w * 16 + llo) * 64 + ua]);
            #pragma unroll
            for (int nt = 0; nt < 4; ++nt) {
                bf16x8_t b = *(const bf16x8_t*)(&Bl[(nt * 16 + llo) * 64 + ua]);
                acc[nt] = __builtin_amdgcn_mfma_f32_16x16x32_bf16(a, b, acc[nt], 0, 0, 0);
            }
        }
        __syncthreads();
    }
    #pragma unroll
    for (int nt = 0; nt < 4; ++nt) {
        int ng = n0 + nt * 16 + llo;
        float bv = bias[ng];
        #pragma unroll
        for (int r = 0; r < 4; ++r) {
            int ig = row0 + w * 16 + lhi * 4 + r;
            out[ig * 256 + ng] = acc[nt][r] + bv;
        }
    }
}

// ---------------- launcher ----------------
extern "C" void kernel_launch(void* const* d_in, const int* in_sizes, int n_in,
                              void* d_out, int out_size, void* d_ws, size_t ws_size,
                              hipStream_t stream)
{
    const float* x    = (const float*)d_in[0];
    const float* vc   = (const float*)d_in[1];
    const float* Wqk  = (const float*)d_in[2];
    const float* Wv   = (const float*)d_in[3];
    const float* Wpj  = (const float*)d_in[4];
    const float* bpj  = (const float*)d_in[5];
    const float* Wpos = (const float*)d_in[6];
    const float* bpos = (const float*)d_in[7];
    const float* gat  = (const float*)d_in[8];
    float* out = (float*)d_out;

    char* ws = (char*)d_ws;
    unsigned short* Wqk_t = (unsigned short*)(ws + 0);          // 256 KB
    unsigned short* Wv_t  = (unsigned short*)(ws + 262144);     // 128 KB
    unsigned short* Wp_t  = (unsigned short*)(ws + 393216);     // 128 KB
    unsigned short* q_ws  = (unsigned short*)(ws + 524288);     // 2 MB
    unsigned short* k_ws  = (unsigned short*)(ws + 2621440);    // 2 MB
    unsigned short* v_ws  = (unsigned short*)(ws + 4718592);    // 2 MB
    unsigned short* o_ws  = (unsigned short*)(ws + 6815744);    // 2 MB

    hipLaunchKernelGGL(k_convert, dim3(64), dim3(256), 0, stream,
                       Wqk, Wv, Wpj, Wqk_t, Wv_t, Wp_t);
    hipLaunchKernelGGL(k_qkv, dim3(12, 64), dim3(256), 0, stream,
                       x, Wqk_t, Wv_t, q_ws, k_ws, v_ws);
    hipLaunchKernelGGL(k_attn, dim3(512), dim3(512), 0, stream,
                       q_ws, k_ws, v_ws, vc, Wpos, bpos, gat, o_ws);
    hipLaunchKernelGGL(k_proj, dim3(4, 64), dim3(256), 0, stream,
                       o_ws, Wp_t, bpj, out);
}

// Round 5
// 117.490 us; speedup vs baseline: 1.2209x; 1.0527x over previous
//
#include <hip/hip_runtime.h>
#include <hip/hip_bf16.h>

// ---------------- problem constants ----------------
// B=4, N=1024, C=256, H=8, HD=32, SCALE=HD^-0.5
#define LOG2E 1.4426950408889634f

typedef __attribute__((ext_vector_type(8))) short bf16x8_t;   // 8 bf16 (4 VGPRs) — mfma A/B frag
typedef __attribute__((ext_vector_type(4))) float f32x4_t;    // mfma C/D frag
typedef __attribute__((ext_vector_type(4))) short s16x4_t;    // 4 bf16 (2 VGPRs) — tr_b16 result

#if __has_builtin(__builtin_amdgcn_exp2f)
#define EXP2F_(x) __builtin_amdgcn_exp2f(x)
#else
__device__ __forceinline__ float EXP2F_(float x) {
    float r; asm volatile("v_exp_f32 %0, %1\ns_nop 1" : "=v"(r) : "v"(x)); return r;
}
#endif
#if __has_builtin(__builtin_amdgcn_sqrtf)
#define SQRTF_(x) __builtin_amdgcn_sqrtf(x)
#else
__device__ __forceinline__ float SQRTF_(float x) {
    float r; asm volatile("v_sqrt_f32 %0, %1\ns_nop 1" : "=v"(r) : "v"(x)); return r;
}
#endif

__device__ __forceinline__ unsigned short f2bf(float f) {
    unsigned u = __float_as_uint(f);
    u += 0x7fffu + ((u >> 16) & 1u);      // RNE
    return (unsigned short)(u >> 16);
}

// pack 2 f32 -> u32 of 2 bf16 (lo = first) — compiles to v_cvt_pk_bf16_f32
__device__ __forceinline__ unsigned pk2(float lo, float hi) {
    union { __hip_bfloat162 h2; unsigned u; } cvt;
    cvt.h2 = __float22bfloat162_rn(make_float2(lo, hi));
    return cvt.u;
}

// global(per-lane) -> LDS(wave-uniform base + lane*16) direct 16B copy
__device__ __forceinline__ void stage16(const unsigned short* g, unsigned short* l, int lane) {
#if __has_builtin(__builtin_amdgcn_global_load_lds)
    __builtin_amdgcn_global_load_lds((const __attribute__((address_space(1))) void*)g,
                                     (__attribute__((address_space(3))) void*)l, 16, 0, 0);
#else
    *(uint4*)((char*)l + lane * 16) = *(const uint4*)g;
#endif
}

__device__ __forceinline__ unsigned lds_off(const void* p) {
    return (unsigned)(size_t)(const __attribute__((address_space(3))) void*)p;
}

// hardware transpose read: [4][16] bf16 block at (addr & ~127), lane llo gets column llo,
// elems = rows. addr must be blockbase + (lane&15)*8 bytes.
__device__ __forceinline__ s16x4_t TR16(unsigned addr) {
    s16x4_t r;
    asm volatile("ds_read_b64_tr_b16 %0, %1" : "=v"(r) : "v"(addr) : "memory");
    return r;
}
__device__ __forceinline__ void tr_fence() {
    asm volatile("s_waitcnt lgkmcnt(0)" ::: "memory");
    __builtin_amdgcn_sched_barrier(0);
}

// ---------------- kernel 1: weight transposes f32->bf16 + pos j-table precompute ----------------
__global__ __launch_bounds__(256) void k_convert(
    const float* __restrict__ Wqk, const float* __restrict__ Wv,
    const float* __restrict__ Wpj, const float* __restrict__ coords,
    const float* __restrict__ W_pos,
    unsigned short* __restrict__ Wqk_t, unsigned short* __restrict__ Wv_t,
    unsigned short* __restrict__ Wp_t, float4* __restrict__ tbl)
{
    __shared__ unsigned short T[64 * 72];
    const int bid = blockIdx.x, tid = threadIdx.x;
    if (bid < 64) {
        const float* src; unsigned short* dst; int N_, kt, nt;
        if (bid < 32)      { src = Wqk; dst = Wqk_t; N_ = 512; kt = bid & 3; nt = bid >> 2; }
        else if (bid < 48) { int t = bid - 32; src = Wv;  dst = Wv_t; N_ = 256; kt = t & 3; nt = t >> 2; }
        else               { int t = bid - 48; src = Wpj; dst = Wp_t; N_ = 256; kt = t & 3; nt = t >> 2; }
        const int kr = tid >> 2, seg = tid & 3;
        #pragma unroll
        for (int u = 0; u < 4; ++u) {
            float4 v = *(const float4*)(src + (kt * 64 + kr) * N_ + nt * 64 + seg * 16 + u * 4);
            T[(seg * 16 + u * 4 + 0) * 72 + kr] = f2bf(v.x);
            T[(seg * 16 + u * 4 + 1) * 72 + kr] = f2bf(v.y);
            T[(seg * 16 + u * 4 + 2) * 72 + kr] = f2bf(v.z);
            T[(seg * 16 + u * 4 + 3) * 72 + kr] = f2bf(v.w);
        }
        __syncthreads();
        const int n = tid >> 2, s2 = tid & 3;
        uint4 a = *(uint4*)&T[n * 72 + s2 * 16];
        uint4 b2 = *(uint4*)&T[n * 72 + s2 * 16 + 8];
        *(uint4*)(dst + (nt * 64 + n) * 256 + kt * 64 + s2 * 16) = a;
        *(uint4*)(dst + (nt * 64 + n) * 256 + kt * 64 + s2 * 16 + 8) = b2;
    } else {
        // pos table: tbl[bh][j] = {x, y, z, log2e*(w_h · p_j)}  (bias NOT folded)
        const int bh = bid - 64, b = bh >> 3, h = bh & 7;
        const float wxl = W_pos[0 * 8 + h] * LOG2E;
        const float wyl = W_pos[1 * 8 + h] * LOG2E;
        const float wzl = W_pos[2 * 8 + h] * LOG2E;
        for (int jl = tid; jl < 1024; jl += 256) {
            float x = coords[(b * 1024 + jl) * 3 + 0];
            float y = coords[(b * 1024 + jl) * 3 + 1];
            float z = coords[(b * 1024 + jl) * 3 + 2];
            tbl[bh * 1024 + jl] = make_float4(x, y, z, fmaf(wxl, x, fmaf(wyl, y, wzl * z)));
        }
    }
}

// ---------------- kernel 2: QKV projection GEMM (M=4096, N=768, K=256) ----------------
// A staged from f32 x with in-flight cvt; B via gload_lds. q pre-scaled by SCALE*log2e.
// v written SUBTILED per bh: [i/4][d/16][4][16] (tr_b16-ready).
__global__ __launch_bounds__(256) void k_qkv(
    const float* __restrict__ x,
    const unsigned short* __restrict__ Wqk_t,
    const unsigned short* __restrict__ Wv_t,
    unsigned short* __restrict__ q_ws, unsigned short* __restrict__ k_ws,
    unsigned short* __restrict__ v_ws)
{
    __shared__ unsigned short Al[64 * 64];   // [r][64], 128B rows, 16B-unit XOR swizzle u^(r&7)
    __shared__ unsigned short Bl[64 * 64];
    const int tid = threadIdx.x;
    const int n0 = blockIdx.x * 64;
    const int row0 = blockIdx.y * 64;
    const int w = tid >> 6, lane = tid & 63;
    const int lhi = lane >> 4, llo = lane & 15;
    const unsigned short* Bsrc = (n0 < 512) ? (Wqk_t + n0 * 256) : (Wv_t + (n0 - 512) * 256);

    const int sr = lane >> 3, sc = lane & 7;
    const int scx = sc ^ sr;                           // pre-swizzled source column unit

    f32x4_t acc[4] = {};
    for (int kc = 0; kc < 4; ++kc) {
        #pragma unroll
        for (int s = 0; s < 2; ++s) {
            int chunk = w * 2 + s;
            int r = chunk * 8 + sr;
            const float* ax = x + (row0 + r) * 256 + kc * 64 + scx * 8;
            float4 a0 = *(const float4*)ax, a1 = *(const float4*)(ax + 4);
            uint4 pk;
            pk.x = pk2(a0.x, a0.y); pk.y = pk2(a0.z, a0.w);
            pk.z = pk2(a1.x, a1.y); pk.w = pk2(a1.z, a1.w);
            *(uint4*)(&Al[r * 64 + sc * 8]) = pk;
            stage16(Bsrc + r * 256 + kc * 64 + scx * 8, &Bl[chunk * 512], lane);
        }
        __syncthreads();
        #pragma unroll
        for (int ks = 0; ks < 2; ++ks) {
            int ua = ((ks * 4 + lhi) ^ (llo & 7)) * 8;
            bf16x8_t a = *(const bf16x8_t*)(&Al[(w * 16 + llo) * 64 + ua]);
            #pragma unroll
            for (int nt = 0; nt < 4; ++nt) {
                bf16x8_t b = *(const bf16x8_t*)(&Bl[(nt * 16 + llo) * 64 + ua]);
                acc[nt] = __builtin_amdgcn_mfma_f32_16x16x32_bf16(a, b, acc[nt], 0, 0, 0);
            }
        }
        __syncthreads();
    }
    constexpr float QSC = (float)(1.4426950408889634 / 5.656854249492380195206754896838);
    #pragma unroll
    for (int nt = 0; nt < 4; ++nt) {
        int ng = n0 + nt * 16 + llo;
        #pragma unroll
        for (int r = 0; r < 4; ++r) {
            int ig = row0 + w * 16 + lhi * 4 + r;
            float val = acc[nt][r];
            int b = ig >> 10, i = ig & 1023;
            if (ng < 256) {
                int h = ng >> 5, d = ng & 31;
                q_ws[((b * 8 + h) * 1024 + i) * 32 + d] = f2bf(val * QSC);
            } else if (ng < 512) {
                int c = ng - 256, h = c >> 5, d = c & 31;
                k_ws[((b * 8 + h) * 1024 + i) * 32 + d] = f2bf(val);
            } else {
                int c = ng - 512, h = c >> 5, d = c & 31;
                v_ws[(size_t)(b * 8 + h) * 32768 +
                     ((i >> 2) * 2 + (d >> 4)) * 64 + (i & 3) * 16 + (d & 15)] = f2bf(val);
            }
        }
    }
}

// ---------------- kernel 3: fused dual-softmax attention ----------------
// grid: 512 blocks = 32 bh x 16 it (XCD-swizzled); 512 threads = 8 waves (4 wi x 2 wj)
// pos-softmax computed TRANSPOSED (lane=j) from global tbl, written [4j][16i]-blocked,
// consumed (and V) via ds_read_b64_tr_b16. Epilogue: LDS combine + gate + normalize.
__global__ __launch_bounds__(512, 2) void k_attn(
    const unsigned short* __restrict__ q_ws,
    const unsigned short* __restrict__ k_ws,
    const unsigned short* __restrict__ v_ws,
    const float4* __restrict__ tbl,
    const float* __restrict__ W_pos,
    const float* __restrict__ b_pos,
    const float* __restrict__ gating,
    unsigned short* __restrict__ o_ws)
{
    __shared__ __align__(16) unsigned short Kl[2 * 64 * 32];   // 8 KB [wj][j][d] 64B rows
    __shared__ __align__(16) unsigned short Vt[2 * 64 * 32];   // 8 KB [wj] subtiled [j/4][d/16][4][16]
    __shared__ __align__(16) unsigned short Wp[2 * 64 * 64];   // 16 KB [wj][i][j] swizzled units
    __shared__ __align__(16) unsigned short Eq[8 * 64 * 16];   // 16 KB per-wave [j/4][4][16i] blocks

    const int tid = threadIdx.x;
    const int bid = blockIdx.x;
    const int xcd = bid & 7, s = bid >> 3;
    const int bh = xcd * 4 + (s >> 4);
    const int it = s & 15;
    const int b = bh >> 3, h = bh & 7;

    const int w = tid >> 6, lane = tid & 63;
    const int wi = w & 3, wj = w >> 2;
    const int lhi = lane >> 4, llo = lane & 15;

    const float wdl = W_pos[3 * 8 + h] * LOG2E;
    const float bpl = b_pos[h] * LOG2E;

    const int i_base = it * 64 + wi * 16;
    // qf = B-frag of swapped QK^T: lane llo = i, elems d = lhi*8+e
    bf16x8_t qf = *(const bf16x8_t*)(q_ws + (bh * 1024 + i_base + llo) * 32 + lhi * 8);

    const float4* tb4 = tbl + (size_t)bh * 1024;
    // wave-uniform i-constants, half-selected per lane (lane handles i = (lane&1)*8 + e)
    float xi8[8], yi8[8], zi8[8], ci8[8];
    const bool hsel = (lane & 1);
    #pragma unroll
    for (int e = 0; e < 8; ++e) {
        float4 lo = tb4[i_base + e];
        float4 hi = tb4[i_base + 8 + e];
        xi8[e] = hsel ? hi.x : lo.x;
        yi8[e] = hsel ? hi.y : lo.y;
        zi8[e] = hsel ? hi.z : lo.z;
        ci8[e] = hsel ? hi.w : lo.w;
    }

    bf16x8_t ones;
    #pragma unroll
    for (int e = 0; e < 8; ++e) ones[e] = (short)0x3F80;   // bf16 1.0

    f32x4_t accP[2] = {}, accQ[2] = {};
    f32x4_t accLp = {}, accLq = {};

    // lane's j assignment for transposed pos-compute (write at byte lane*16 of Eq tile)
    const int jl1 = ((lane >> 3) << 2) + ((lane & 7) >> 1);
    unsigned short* eqw = &Eq[w * 1024];
    const unsigned eqbase = lds_off(&Eq[w * 1024]) + lhi * 256 + llo * 8;
    const unsigned vtbase = lds_off(&Vt[wj * 2048]) + lhi * 512 + llo * 8;

    for (int t = 0; t < 8; ++t) {
        const int j0 = wj * 512 + t * 64;
        // --- stage K (DMA), V (DMA, subtiled), and this lane's 2 j-table entries ---
        stage16(k_ws + (bh * 1024 + j0 + wi * 16 + (lane >> 2)) * 32 + (lane & 3) * 8,
                &Kl[wj * 2048 + wi * 512], lane);
        stage16(v_ws + (size_t)bh * 32768 + j0 * 32 + wi * 512 + lane * 8,
                &Vt[wj * 2048 + wi * 512], lane);
        float4 t1 = tb4[j0 + jl1];
        float4 t2 = tb4[j0 + jl1 + 32];
        __syncthreads();

        // --- transposed pos-softmax numerators: lane = (j, i-half), 16 eq values ---
        {
            float aj1 = t1.w + bpl, aj2 = t2.w + bpl;
            float eq1[8], eq2[8];
            #pragma unroll
            for (int e = 0; e < 8; ++e) {
                float dx = t1.x - xi8[e], dy = t1.y - yi8[e], dz = t1.z - zi8[e];
                float d2 = fmaf(dx, dx, fmaf(dy, dy, dz * dz));
                eq1[e] = EXP2F_(fmaf(wdl, SQRTF_(d2), aj1 - ci8[e]));
                float ex = t2.x - xi8[e], ey = t2.y - yi8[e], ez = t2.z - zi8[e];
                float e2 = fmaf(ex, ex, fmaf(ey, ey, ez * ez));
                eq2[e] = EXP2F_(fmaf(wdl, SQRTF_(e2), aj2 - ci8[e]));
            }
            uint4 u1, u2;
            u1.x = pk2(eq1[0], eq1[1]); u1.y = pk2(eq1[2], eq1[3]);
            u1.z = pk2(eq1[4], eq1[5]); u1.w = pk2(eq1[6], eq1[7]);
            u2.x = pk2(eq2[0], eq2[1]); u2.y = pk2(eq2[2], eq2[3]);
            u2.z = pk2(eq2[4], eq2[5]); u2.w = pk2(eq2[6], eq2[7]);
            *(uint4*)(&eqw[lane * 8]) = u1;          // j block rows jl1,   conflict-free
            *(uint4*)(&eqw[512 + lane * 8]) = u2;    // j block rows jl1+32
        }

        // --- swapped QK^T content path: sv = mfma(K,Q) -> lane: i=llo, j=jq*16+lhi*4+r ---
        #pragma unroll
        for (int jq = 0; jq < 4; ++jq) {
            bf16x8_t kf = *(const bf16x8_t*)(&Kl[wj * 2048 + (jq * 16 + llo) * 32 + lhi * 8]);
            f32x4_t zero = {};
            f32x4_t sv = __builtin_amdgcn_mfma_f32_16x16x32_bf16(kf, qf, zero, 0, 0, 0);
            float ep0 = EXP2F_(sv[0]), ep1 = EXP2F_(sv[1]);
            float ep2 = EXP2F_(sv[2]), ep3 = EXP2F_(sv[3]);
            int off = (wj * 64 + wi * 16 + llo) * 64 +
                      (((jq * 2 + (lhi >> 1)) ^ (llo & 7)) * 8) + (lhi & 1) * 4;
            uint2 uP;
            uP.x = pk2(ep0, ep1); uP.y = pk2(ep2, ep3);
            *(uint2*)(&Wp[off]) = uP;
        }

        // --- PV + L-rows (tr_b16 reads for V and Eq; bP from Wp) ---
        #pragma unroll
        for (int jb = 0; jb < 2; ++jb) {
            int uu = ((jb * 4 + lhi) ^ (llo & 7)) * 8;
            bf16x8_t bP = *(const bf16x8_t*)(&Wp[(wj * 64 + wi * 16 + llo) * 64 + uu]);
            s16x4_t q0 = TR16(eqbase + jb * 1024);
            s16x4_t q1 = TR16(eqbase + jb * 1024 + 128);
            s16x4_t a00 = TR16(vtbase + jb * 2048 + 0);
            s16x4_t a01 = TR16(vtbase + jb * 2048 + 256);
            s16x4_t a10 = TR16(vtbase + jb * 2048 + 128);
            s16x4_t a11 = TR16(vtbase + jb * 2048 + 384);
            tr_fence();
            bf16x8_t bQ  = __builtin_shufflevector(q0, q1, 0, 1, 2, 3, 4, 5, 6, 7);
            bf16x8_t af0 = __builtin_shufflevector(a00, a01, 0, 1, 2, 3, 4, 5, 6, 7);
            bf16x8_t af1 = __builtin_shufflevector(a10, a11, 0, 1, 2, 3, 4, 5, 6, 7);
            accLp = __builtin_amdgcn_mfma_f32_16x16x32_bf16(ones, bP, accLp, 0, 0, 0);
            accLq = __builtin_amdgcn_mfma_f32_16x16x32_bf16(ones, bQ, accLq, 0, 0, 0);
            accP[0] = __builtin_amdgcn_mfma_f32_16x16x32_bf16(af0, bP, accP[0], 0, 0, 0);
            accQ[0] = __builtin_amdgcn_mfma_f32_16x16x32_bf16(af0, bQ, accQ[0], 0, 0, 0);
            accP[1] = __builtin_amdgcn_mfma_f32_16x16x32_bf16(af1, bP, accP[1], 0, 0, 0);
            accQ[1] = __builtin_amdgcn_mfma_f32_16x16x32_bf16(af1, bQ, accQ[1], 0, 0, 0);
        }
        __syncthreads();
    }

    // --- epilogue: cross-half combine in LDS (reuse Wp/Eq), gate+normalize, write o_ws ---
    float* red = (float*)Wp;     // 4096 f32: [wi*64+lane][16]
    float* LPQ = (float*)Eq;     // [0..63] Lp, [64..127] Lq
    if (wj == 1) {
        float* pr = red + (wi * 64 + lane) * 16;
        *(f32x4_t*)(pr + 0) = accP[0]; *(f32x4_t*)(pr + 4)  = accP[1];
        *(f32x4_t*)(pr + 8) = accQ[0]; *(f32x4_t*)(pr + 12) = accQ[1];
        if (lhi == 0) { LPQ[wi * 16 + llo] = accLp[0]; LPQ[64 + wi * 16 + llo] = accLq[0]; }
    }
    __syncthreads();
    if (wj == 0) {
        const float* pr = red + (wi * 64 + lane) * 16;
        float Lp = accLp[0] + LPQ[wi * 16 + llo];
        float Lq = accLq[0] + LPQ[64 + wi * 16 + llo];
        float sig = 1.0f / (1.0f + __expf(-gating[h]));
        float ca = (1.0f - sig) / Lp, cb2 = sig / Lq;
        int rowg = b * 1024 + it * 64 + wi * 16 + llo;
        #pragma unroll
        for (int dt = 0; dt < 2; ++dt) {
            float o0 = ca * (accP[dt][0] + pr[dt * 4 + 0]) + cb2 * (accQ[dt][0] + pr[8 + dt * 4 + 0]);
            float o1 = ca * (accP[dt][1] + pr[dt * 4 + 1]) + cb2 * (accQ[dt][1] + pr[8 + dt * 4 + 1]);
            float o2 = ca * (accP[dt][2] + pr[dt * 4 + 2]) + cb2 * (accQ[dt][2] + pr[8 + dt * 4 + 2]);
            float o3 = ca * (accP[dt][3] + pr[dt * 4 + 3]) + cb2 * (accQ[dt][3] + pr[8 + dt * 4 + 3]);
            uint2 uu;
            uu.x = pk2(o0, o1); uu.y = pk2(o2, o3);
            *(uint2*)(o_ws + (size_t)rowg * 256 + h * 32 + dt * 16 + lhi * 4) = uu;
        }
    }
}

// ---------------- kernel 4: output projection GEMM (M=4096, N=256, K=256) + bias ----------------
__global__ __launch_bounds__(256) void k_proj(
    const unsigned short* __restrict__ A,
    const unsigned short* __restrict__ Bt,
    const float* __restrict__ bias,
    float* __restrict__ out)
{
    __shared__ unsigned short Al[64 * 64];
    __shared__ unsigned short Bl[64 * 64];
    const int tid = threadIdx.x;
    const int n0 = blockIdx.x * 64;
    const int row0 = blockIdx.y * 64;
    const int w = tid >> 6, lane = tid & 63;
    const int lhi = lane >> 4, llo = lane & 15;
    const int sr = lane >> 3, sc = lane & 7;
    const int scx = sc ^ sr;

    f32x4_t acc[4] = {};
    for (int kc = 0; kc < 4; ++kc) {
        #pragma unroll
        for (int s = 0; s < 2; ++s) {
            int chunk = w * 2 + s;
            int r = chunk * 8 + sr;
            stage16(A + (row0 + r) * 256 + kc * 64 + scx * 8, &Al[chunk * 512], lane);
            stage16(Bt + (n0 + r) * 256 + kc * 64 + scx * 8, &Bl[chunk * 512], lane);
        }
        __syncthreads();
        #pragma unroll
        for (int ks = 0; ks < 2; ++ks) {
            int ua = ((ks * 4 + lhi) ^ (llo & 7)) * 8;
            bf16x8_t a = *(const bf16x8_t*)(&Al[(w * 16 + llo) * 64 + ua]);
            #pragma unroll
            for (int nt = 0; nt < 4; ++nt) {
                bf16x8_t b = *(const bf16x8_t*)(&Bl[(nt * 16 + llo) * 64 + ua]);
                acc[nt] = __builtin_amdgcn_mfma_f32_16x16x32_bf16(a, b, acc[nt], 0, 0, 0);
            }
        }
        __syncthreads();
    }
    #pragma unroll
    for (int nt = 0; nt < 4; ++nt) {
        int ng = n0 + nt * 16 + llo;
        float bv = bias[ng];
        #pragma unroll
        for (int r = 0; r < 4; ++r) {
            int ig = row0 + w * 16 + lhi * 4 + r;
            out[ig * 256 + ng] = acc[nt][r] + bv;
        }
    }
}

// ---------------- launcher ----------------
extern "C" void kernel_launch(void* const* d_in, const int* in_sizes, int n_in,
                              void* d_out, int out_size, void* d_ws, size_t ws_size,
                              hipStream_t stream)
{
    const float* x    = (const float*)d_in[0];
    const float* vc   = (const float*)d_in[1];
    const float* Wqk  = (const float*)d_in[2];
    const float* Wv   = (const float*)d_in[3];
    const float* Wpj  = (const float*)d_in[4];
    const float* bpj  = (const float*)d_in[5];
    const float* Wpos = (const float*)d_in[6];
    const float* bpos = (const float*)d_in[7];
    const float* gat  = (const float*)d_in[8];
    float* out = (float*)d_out;

    char* ws = (char*)d_ws;
    unsigned short* Wqk_t = (unsigned short*)(ws + 0);          // 256 KB
    unsigned short* Wv_t  = (unsigned short*)(ws + 262144);     // 128 KB
    unsigned short* Wp_t  = (unsigned short*)(ws + 393216);     // 128 KB
    unsigned short* q_ws  = (unsigned short*)(ws + 524288);     // 2 MB
    unsigned short* k_ws  = (unsigned short*)(ws + 2621440);    // 2 MB
    unsigned short* v_ws  = (unsigned short*)(ws + 4718592);    // 2 MB (subtiled)
    unsigned short* o_ws  = (unsigned short*)(ws + 6815744);    // 2 MB
    float4*         tbl   = (float4*)(ws + 8912896);            // 512 KB pos j-table

    hipLaunchKernelGGL(k_convert, dim3(96), dim3(256), 0, stream,
                       Wqk, Wv, Wpj, vc, Wpos, Wqk_t, Wv_t, Wp_t, tbl);
    hipLaunchKernelGGL(k_qkv, dim3(12, 64), dim3(256), 0, stream,
                       x, Wqk_t, Wv_t, q_ws, k_ws, v_ws);
    hipLaunchKernelGGL(k_attn, dim3(512), dim3(512), 0, stream,
                       q_ws, k_ws, v_ws, tbl, Wpos, bpos, gat, o_ws);
    hipLaunchKernelGGL(k_proj, dim3(4, 64), dim3(256), 0, stream,
                       o_ws, Wp_t, bpj, out);
}

// Round 7
// 115.395 us; speedup vs baseline: 1.2431x; 1.0182x over previous
//
#include <hip/hip_runtime.h>
#include <hip/hip_bf16.h>

// ---------------- problem constants ----------------
// B=4, N=1024, C=256, H=8, HD=32, SCALE=HD^-0.5
#define LOG2E 1.4426950408889634f

typedef __attribute__((ext_vector_type(8))) short bf16x8_t;   // 8 bf16 (4 VGPRs) — mfma A/B frag
typedef __attribute__((ext_vector_type(4))) float f32x4_t;    // mfma C/D frag

#if __has_builtin(__builtin_amdgcn_exp2f)
#define EXP2F_(x) __builtin_amdgcn_exp2f(x)
#else
__device__ __forceinline__ float EXP2F_(float x) {
    float r; asm volatile("v_exp_f32 %0, %1\ns_nop 1" : "=v"(r) : "v"(x)); return r;
}
#endif
#if __has_builtin(__builtin_amdgcn_sqrtf)
#define SQRTF_(x) __builtin_amdgcn_sqrtf(x)
#else
__device__ __forceinline__ float SQRTF_(float x) {
    float r; asm volatile("v_sqrt_f32 %0, %1\ns_nop 1" : "=v"(r) : "v"(x)); return r;
}
#endif

__device__ __forceinline__ unsigned short f2bf(float f) {
    unsigned u = __float_as_uint(f);
    u += 0x7fffu + ((u >> 16) & 1u);      // RNE
    return (unsigned short)(u >> 16);
}

// pack 2 f32 -> u32 of 2 bf16 (lo = first) — compiles to v_cvt_pk_bf16_f32
__device__ __forceinline__ unsigned pk2(float lo, float hi) {
    union { __hip_bfloat162 h2; unsigned u; } cvt;
    cvt.h2 = __float22bfloat162_rn(make_float2(lo, hi));
    return cvt.u;
}

// global(per-lane) -> LDS(wave-uniform base + lane*16) direct 16B copy
__device__ __forceinline__ void stage16(const void* g, void* l, int lane) {
#if __has_builtin(__builtin_amdgcn_global_load_lds)
    __builtin_amdgcn_global_load_lds((const __attribute__((address_space(1))) void*)g,
                                     (__attribute__((address_space(3))) void*)l, 16, 0, 0);
#else
    *(uint4*)((char*)l + lane * 16) = *(const uint4*)g;
#endif
}

// ---------------- kernel 1: weight transposes f32->bf16 + pos j-table precompute ----------------
__global__ __launch_bounds__(256) void k_convert(
    const float* __restrict__ Wqk, const float* __restrict__ Wv,
    const float* __restrict__ Wpj, const float* __restrict__ coords,
    const float* __restrict__ W_pos,
    unsigned short* __restrict__ Wqk_t, unsigned short* __restrict__ Wv_t,
    unsigned short* __restrict__ Wp_t, float4* __restrict__ tbl)
{
    __shared__ unsigned short T[64 * 72];
    const int bid = blockIdx.x, tid = threadIdx.x;
    if (bid < 64) {
        const float* src; unsigned short* dst; int N_, kt, nt;
        if (bid < 32)      { src = Wqk; dst = Wqk_t; N_ = 512; kt = bid & 3; nt = bid >> 2; }
        else if (bid < 48) { int t = bid - 32; src = Wv;  dst = Wv_t; N_ = 256; kt = t & 3; nt = t >> 2; }
        else               { int t = bid - 48; src = Wpj; dst = Wp_t; N_ = 256; kt = t & 3; nt = t >> 2; }
        const int kr = tid >> 2, seg = tid & 3;
        #pragma unroll
        for (int u = 0; u < 4; ++u) {
            float4 v = *(const float4*)(src + (kt * 64 + kr) * N_ + nt * 64 + seg * 16 + u * 4);
            T[(seg * 16 + u * 4 + 0) * 72 + kr] = f2bf(v.x);
            T[(seg * 16 + u * 4 + 1) * 72 + kr] = f2bf(v.y);
            T[(seg * 16 + u * 4 + 2) * 72 + kr] = f2bf(v.z);
            T[(seg * 16 + u * 4 + 3) * 72 + kr] = f2bf(v.w);
        }
        __syncthreads();
        const int n = tid >> 2, s2 = tid & 3;
        uint4 a = *(uint4*)&T[n * 72 + s2 * 16];
        uint4 b2 = *(uint4*)&T[n * 72 + s2 * 16 + 8];
        *(uint4*)(dst + (nt * 64 + n) * 256 + kt * 64 + s2 * 16) = a;
        *(uint4*)(dst + (nt * 64 + n) * 256 + kt * 64 + s2 * 16 + 8) = b2;
    } else {
        // pos table: tbl[bh][j] = {x, y, z, log2e*(w_h · p_j)}  (bias NOT folded)
        const int bh = bid - 64, b = bh >> 3, h = bh & 7;
        const float wxl = W_pos[0 * 8 + h] * LOG2E;
        const float wyl = W_pos[1 * 8 + h] * LOG2E;
        const float wzl = W_pos[2 * 8 + h] * LOG2E;
        for (int jl = tid; jl < 1024; jl += 256) {
            float x = coords[(b * 1024 + jl) * 3 + 0];
            float y = coords[(b * 1024 + jl) * 3 + 1];
            float z = coords[(b * 1024 + jl) * 3 + 2];
            tbl[bh * 1024 + jl] = make_float4(x, y, z, fmaf(wxl, x, fmaf(wyl, y, wzl * z)));
        }
    }
}

// ---------------- kernel 2: QKV projection GEMM (M=4096, N=768, K=256) ----------------
// A staged from f32 x with in-flight cvt; B via gload_lds. q pre-scaled by SCALE*log2e.
// v written j-octet-subtiled per bh: element (j,d) at [(j>>3)*32 + d]*8 + (j&7).
__global__ __launch_bounds__(256) void k_qkv(
    const float* __restrict__ x,
    const unsigned short* __restrict__ Wqk_t,
    const unsigned short* __restrict__ Wv_t,
    unsigned short* __restrict__ q_ws, unsigned short* __restrict__ k_ws,
    unsigned short* __restrict__ v_ws)
{
    __shared__ unsigned short Al[64 * 64];   // [r][64], 128B rows, 16B-unit XOR swizzle u^(r&7)
    __shared__ unsigned short Bl[64 * 64];
    const int tid = threadIdx.x;
    const int n0 = blockIdx.x * 64;
    const int row0 = blockIdx.y * 64;
    const int w = tid >> 6, lane = tid & 63;
    const int lhi = lane >> 4, llo = lane & 15;
    const unsigned short* Bsrc = (n0 < 512) ? (Wqk_t + n0 * 256) : (Wv_t + (n0 - 512) * 256);

    const int sr = lane >> 3, sc = lane & 7;
    const int scx = sc ^ sr;                           // pre-swizzled source column unit

    f32x4_t acc[4] = {};
    for (int kc = 0; kc < 4; ++kc) {
        #pragma unroll
        for (int s = 0; s < 2; ++s) {
            int chunk = w * 2 + s;
            int r = chunk * 8 + sr;
            const float* ax = x + (row0 + r) * 256 + kc * 64 + scx * 8;
            float4 a0 = *(const float4*)ax, a1 = *(const float4*)(ax + 4);
            uint4 pk;
            pk.x = pk2(a0.x, a0.y); pk.y = pk2(a0.z, a0.w);
            pk.z = pk2(a1.x, a1.y); pk.w = pk2(a1.z, a1.w);
            *(uint4*)(&Al[r * 64 + sc * 8]) = pk;
            stage16(Bsrc + r * 256 + kc * 64 + scx * 8, &Bl[chunk * 512], lane);
        }
        __syncthreads();
        #pragma unroll
        for (int ks = 0; ks < 2; ++ks) {
            int ua = ((ks * 4 + lhi) ^ (llo & 7)) * 8;
            bf16x8_t a = *(const bf16x8_t*)(&Al[(w * 16 + llo) * 64 + ua]);
            #pragma unroll
            for (int nt = 0; nt < 4; ++nt) {
                bf16x8_t b = *(const bf16x8_t*)(&Bl[(nt * 16 + llo) * 64 + ua]);
                acc[nt] = __builtin_amdgcn_mfma_f32_16x16x32_bf16(a, b, acc[nt], 0, 0, 0);
            }
        }
        __syncthreads();
    }
    constexpr float QSC = (float)(1.4426950408889634 / 5.656854249492380195206754896838);
    #pragma unroll
    for (int nt = 0; nt < 4; ++nt) {
        int ng = n0 + nt * 16 + llo;
        if (ng < 512) {
            #pragma unroll
            for (int r = 0; r < 4; ++r) {
                int ig = row0 + w * 16 + lhi * 4 + r;
                float val = acc[nt][r];
                int b = ig >> 10, i = ig & 1023;
                if (ng < 256) {
                    int h = ng >> 5, d = ng & 31;
                    q_ws[((b * 8 + h) * 1024 + i) * 32 + d] = f2bf(val * QSC);
                } else {
                    int c = ng - 256, h = c >> 5, d = c & 31;
                    k_ws[((b * 8 + h) * 1024 + i) * 32 + d] = f2bf(val);
                }
            }
        } else {
            // V: pack 4 consecutive-i bf16 -> one uint2, subtiled layout
            int c = ng - 512, h = c >> 5, d = c & 31;
            int i0 = row0 + w * 16 + lhi * 4;          // (i0 & 7) == (lhi&1)*4
            int b = i0 >> 10, i = i0 & 1023;
            uint2 vv;
            vv.x = pk2(acc[nt][0], acc[nt][1]);
            vv.y = pk2(acc[nt][2], acc[nt][3]);
            *(uint2*)(v_ws + (size_t)(b * 8 + h) * 32768 + ((i >> 3) * 32 + d) * 8 + (i & 7)) = vv;
        }
    }
}

// ---------------- kernel 3: fused dual-softmax attention — barrier-free main loop ----------------
// grid: 512 blocks = 32 bh x 16 it (XCD-swizzled); 512 threads = 8 waves (4 wi x 2 wj)
// K,V frags loaded global->reg (L1/L2-resident); pos numerators computed per-lane directly
// in bQ layout (lane = (i=llo, j-octet=lhi)); only same-wave Wp exchange uses LDS.
__global__ __launch_bounds__(512, 4) void k_attn(
    const unsigned short* __restrict__ q_ws,
    const unsigned short* __restrict__ k_ws,
    const unsigned short* __restrict__ v_ws,
    const float4* __restrict__ tbl,
    const float* __restrict__ W_pos,
    const float* __restrict__ b_pos,
    const float* __restrict__ gating,
    unsigned short* __restrict__ o_ws)
{
    __shared__ __align__(16) float4 TBL[1024];                 // 16 KB swizzled j-table
    __shared__ __align__(16) unsigned short Wp[8 * 16 * 64];   // 16 KB per-wave P tiles

    const int tid = threadIdx.x;
    const int bid = blockIdx.x;
    const int xcd = bid & 7, s = bid >> 3;
    const int bh = xcd * 4 + (s >> 4);
    const int it = s & 15;
    const int b = bh >> 3, h = bh & 7;

    const int w = tid >> 6, lane = tid & 63;
    const int wi = w & 3, wj = w >> 2;
    const int lhi = lane >> 4, llo = lane & 15;

    const float wdl = W_pos[3 * 8 + h] * LOG2E;
    const float bpl = b_pos[h] * LOG2E;

    const int i_base = it * 64 + wi * 16;
    // qf = B-frag of swapped QK^T: lane llo = i, elems d = lhi*8+e
    bf16x8_t qf = *(const bf16x8_t*)(q_ws + (bh * 1024 + i_base + llo) * 32 + lhi * 8);

    const float4* tb4 = tbl + (size_t)bh * 1024;
    // per-lane i-constants (i = i_base + llo)
    float4 icst = tb4[i_base + llo];
    const float xi = icst.x, yi = icst.y, zi = icst.z;
    const float cmb = bpl - icst.w;                  // bias - log2e*(w·p_i)

    // stage swizzled j-table: TBL[s] = tb4[s ^ ((s>>3)&7)] (involution; breaks 4-way
    // bank conflict of the lhi-strided broadcast reads)
    #pragma unroll
    for (int r = 0; r < 2; ++r) {
        int sidx = w * 128 + r * 64 + lane;
        stage16(tb4 + (sidx ^ ((sidx >> 3) & 7)), &TBL[w * 128 + r * 64], lane);
    }

    bf16x8_t ones;
    #pragma unroll
    for (int e = 0; e < 8; ++e) ones[e] = (short)0x3F80;   // bf16 1.0

    f32x4_t accP[2] = {}, accQ[2] = {};
    f32x4_t accLp = {}, accLq = {};

    const unsigned short* kbase = k_ws + (size_t)bh * 32768;
    const unsigned short* vbase = v_ws + (size_t)bh * 32768;

    __syncthreads();   // TBL ready — the ONLY barrier before the epilogue

    for (int t = 0; t < 8; ++t) {
        const int j0 = wj * 512 + t * 64;
        // --- issue K/V frag loads (coalesced, L1/L2-resident) ---
        bf16x8_t kf[4], vf[4];
        #pragma unroll
        for (int jq = 0; jq < 4; ++jq)
            kf[jq] = *(const bf16x8_t*)(kbase + (j0 + jq * 16 + llo) * 32 + lhi * 8);
        #pragma unroll
        for (int jb = 0; jb < 2; ++jb)
            #pragma unroll
            for (int dt = 0; dt < 2; ++dt)
                vf[jb * 2 + dt] = *(const bf16x8_t*)(vbase +
                    ((j0 + jb * 32 + lhi * 8) >> 3) * 256 + (dt * 16 + llo) * 8);

        // --- pos numerators straight into bQ regs (lane: i=llo fixed, j=jb*32+lhi*8+e) ---
        bf16x8_t bQ[2];
        #pragma unroll
        for (int jb = 0; jb < 2; ++jb) {
            int jj = j0 + jb * 32 + lhi * 8;
            int xs = (jj >> 3) & 7;
            float eq[8];
            #pragma unroll
            for (int e = 0; e < 8; ++e) {
                float4 cj = TBL[jj + (e ^ xs)];
                float dx = cj.x - xi, dy = cj.y - yi, dz = cj.z - zi;
                float d2 = fmaf(dx, dx, fmaf(dy, dy, dz * dz));
                eq[e] = EXP2F_(fmaf(wdl, SQRTF_(d2), cj.w + cmb));
            }
            uint4 uq;
            uq.x = pk2(eq[0], eq[1]); uq.y = pk2(eq[2], eq[3]);
            uq.z = pk2(eq[4], eq[5]); uq.w = pk2(eq[6], eq[7]);
            bQ[jb] = *(bf16x8_t*)&uq;
        }

        // --- swapped QK^T: sv = mfma(K,Q) -> lane: i=llo, j=jq*16+lhi*4+r ---
        #pragma unroll
        for (int jq = 0; jq < 4; ++jq) {
            f32x4_t zero = {};
            f32x4_t sv = __builtin_amdgcn_mfma_f32_16x16x32_bf16(kf[jq], qf, zero, 0, 0, 0);
            uint2 uP;
            uP.x = pk2(EXP2F_(sv[0]), EXP2F_(sv[1]));
            uP.y = pk2(EXP2F_(sv[2]), EXP2F_(sv[3]));
            int off = (w * 16 + llo) * 64 +
                      (((jq * 2 + (lhi >> 1)) ^ (llo & 7)) * 8) + (lhi & 1) * 4;
            *(uint2*)(&Wp[off]) = uP;
        }

        // --- PV + L-rows (bP via same-wave LDS exchange; compiler inserts lgkmcnt) ---
        #pragma unroll
        for (int jb = 0; jb < 2; ++jb) {
            bf16x8_t bP = *(const bf16x8_t*)(&Wp[(w * 16 + llo) * 64 +
                                                 (((jb * 4 + lhi) ^ (llo & 7)) * 8)]);
            accLp = __builtin_amdgcn_mfma_f32_16x16x32_bf16(ones, bP, accLp, 0, 0, 0);
            accLq = __builtin_amdgcn_mfma_f32_16x16x32_bf16(ones, bQ[jb], accLq, 0, 0, 0);
            accP[0] = __builtin_amdgcn_mfma_f32_16x16x32_bf16(vf[jb * 2 + 0], bP, accP[0], 0, 0, 0);
            accP[1] = __builtin_amdgcn_mfma_f32_16x16x32_bf16(vf[jb * 2 + 1], bP, accP[1], 0, 0, 0);
            accQ[0] = __builtin_amdgcn_mfma_f32_16x16x32_bf16(vf[jb * 2 + 0], bQ[jb], accQ[0], 0, 0, 0);
            accQ[1] = __builtin_amdgcn_mfma_f32_16x16x32_bf16(vf[jb * 2 + 1], bQ[jb], accQ[1], 0, 0, 0);
        }
    }

    // --- epilogue: cross-half combine in LDS (reuse Wp/TBL), gate+normalize, write o_ws ---
    __syncthreads();             // all waves done with Wp/TBL
    float* red = (float*)Wp;     // 4096 f32: [wi*64+lane][16]
    float* LPQ = (float*)TBL;    // [0..63] Lp, [64..127] Lq
    if (wj == 1) {
        float* pr = red + (wi * 64 + lane) * 16;
        *(f32x4_t*)(pr + 0) = accP[0]; *(f32x4_t*)(pr + 4)  = accP[1];
        *(f32x4_t*)(pr + 8) = accQ[0]; *(f32x4_t*)(pr + 12) = accQ[1];
        if (lhi == 0) { LPQ[wi * 16 + llo] = accLp[0]; LPQ[64 + wi * 16 + llo] = accLq[0]; }
    }
    __syncthreads();
    if (wj == 0) {
        const float* pr = red + (wi * 64 + lane) * 16;
        float Lp = accLp[0] + LPQ[wi * 16 + llo];
        float Lq = accLq[0] + LPQ[64 + wi * 16 + llo];
        float sig = 1.0f / (1.0f + __expf(-gating[h]));
        float ca = (1.0f - sig) / Lp, cb2 = sig / Lq;
        int rowg = b * 1024 + it * 64 + wi * 16 + llo;
        #pragma unroll
        for (int dt = 0; dt < 2; ++dt) {
            float o0 = ca * (accP[dt][0] + pr[dt * 4 + 0]) + cb2 * (accQ[dt][0] + pr[8 + dt * 4 + 0]);
            float o1 = ca * (accP[dt][1] + pr[dt * 4 + 1]) + cb2 * (accQ[dt][1] + pr[8 + dt * 4 + 1]);
            float o2 = ca * (accP[dt][2] + pr[dt * 4 + 2]) + cb2 * (accQ[dt][2] + pr[8 + dt * 4 + 2]);
            float o3 = ca * (accP[dt][3] + pr[dt * 4 + 3]) + cb2 * (accQ[dt][3] + pr[8 + dt * 4 + 3]);
            uint2 uu;
            uu.x = pk2(o0, o1); uu.y = pk2(o2, o3);
            *(uint2*)(o_ws + (size_t)rowg * 256 + h * 32 + dt * 16 + lhi * 4) = uu;
        }
    }
}

// ---------------- kernel 4: output projection GEMM (M=4096, N=256, K=256) + bias ----------------
__global__ __launch_bounds__(256) void k_proj(
    const unsigned short* __restrict__ A,
    const unsigned short* __restrict__ Bt,
    const float* __restrict__ bias,
    float* __restrict__ out)
{
    __shared__ unsigned short Al[64 * 64];
    __shared__ unsigned short Bl[64 * 64];
    const int tid = threadIdx.x;
    const int n0 = blockIdx.x * 64;
    const int row0 = blockIdx.y * 64;
    const int w = tid >> 6, lane = tid & 63;
    const int lhi = lane >> 4, llo = lane & 15;
    const int sr = lane >> 3, sc = lane & 7;
    const int scx = sc ^ sr;

    f32x4_t acc[4] = {};
    for (int kc = 0; kc < 4; ++kc) {
        #pragma unroll
        for (int s = 0; s < 2; ++s) {
            int chunk = w * 2 + s;
            int r = chunk * 8 + sr;
            stage16(A + (row0 + r) * 256 + kc * 64 + scx * 8, &Al[chunk * 512], lane);
            stage16(Bt + (n0 + r) * 256 + kc * 64 + scx * 8, &Bl[chunk * 512], lane);
        }
        __syncthreads();
        #pragma unroll
        for (int ks = 0; ks < 2; ++ks) {
            int ua = ((ks * 4 + lhi) ^ (llo & 7)) * 8;
            bf16x8_t a = *(const bf16x8_t*)(&Al[(w * 16 + llo) * 64 + ua]);
            #pragma unroll
            for (int nt = 0; nt < 4; ++nt) {
                bf16x8_t b = *(const bf16x8_t*)(&Bl[(nt * 16 + llo) * 64 + ua]);
                acc[nt] = __builtin_amdgcn_mfma_f32_16x16x32_bf16(a, b, acc[nt], 0, 0, 0);
            }
        }
        __syncthreads();
    }
    #pragma unroll
    for (int nt = 0; nt < 4; ++nt) {
        int ng = n0 + nt * 16 + llo;
        float bv = bias[ng];
        #pragma unroll
        for (int r = 0; r < 4; ++r) {
            int ig = row0 + w * 16 + lhi * 4 + r;
            out[ig * 256 + ng] = acc[nt][r] + bv;
        }
    }
}

// ---------------- launcher ----------------
extern "C" void kernel_launch(void* const* d_in, const int* in_sizes, int n_in,
                              void* d_out, int out_size, void* d_ws, size_t ws_size,
                              hipStream_t stream)
{
    const float* x    = (const float*)d_in[0];
    const float* vc   = (const float*)d_in[1];
    const float* Wqk  = (const float*)d_in[2];
    const float* Wv   = (const float*)d_in[3];
    const float* Wpj  = (const float*)d_in[4];
    const float* bpj  = (const float*)d_in[5];
    const float* Wpos = (const float*)d_in[6];
    const float* bpos = (const float*)d_in[7];
    const float* gat  = (const float*)d_in[8];
    float* out = (float*)d_out;

    char* ws = (char*)d_ws;
    unsigned short* Wqk_t = (unsigned short*)(ws + 0);          // 256 KB
    unsigned short* Wv_t  = (unsigned short*)(ws + 262144);     // 128 KB
    unsigned short* Wp_t  = (unsigned short*)(ws + 393216);     // 128 KB
    unsigned short* q_ws  = (unsigned short*)(ws + 524288);     // 2 MB
    unsigned short* k_ws  = (unsigned short*)(ws + 2621440);    // 2 MB
    unsigned short* v_ws  = (unsigned short*)(ws + 4718592);    // 2 MB (j-octet subtiled)
    unsigned short* o_ws  = (unsigned short*)(ws + 6815744);    // 2 MB
    float4*         tbl   = (float4*)(ws + 8912896);            // 512 KB pos j-table

    hipLaunchKernelGGL(k_convert, dim3(96), dim3(256), 0, stream,
                       Wqk, Wv, Wpj, vc, Wpos, Wqk_t, Wv_t, Wp_t, tbl);
    hipLaunchKernelGGL(k_qkv, dim3(12, 64), dim3(256), 0, stream,
                       x, Wqk_t, Wv_t, q_ws, k_ws, v_ws);
    hipLaunchKernelGGL(k_attn, dim3(512), dim3(512), 0, stream,
                       q_ws, k_ws, v_ws, tbl, Wpos, bpos, gat, o_ws);
    hipLaunchKernelGGL(k_proj, dim3(4, 64), dim3(256), 0, stream,
                       o_ws, Wp_t, bpj, out);
}

// Round 10
// 109.695 us; speedup vs baseline: 1.3077x; 1.0520x over previous
//
#include <hip/hip_runtime.h>
#include <hip/hip_bf16.h>

// ---------------- problem constants ----------------
// B=4, N=1024, C=256, H=8, HD=32, SCALE=HD^-0.5
#define LOG2E 1.4426950408889634f
#define ONEBF ((unsigned short)0x3F80)

typedef __attribute__((ext_vector_type(8))) short bf16x8_t;   // 8 bf16 (4 VGPRs) — mfma A/B frag
typedef __attribute__((ext_vector_type(4))) float f32x4_t;    // mfma C/D frag

#if __has_builtin(__builtin_amdgcn_exp2f)
#define EXP2F_(x) __builtin_amdgcn_exp2f(x)
#else
__device__ __forceinline__ float EXP2F_(float x) {
    float r; asm volatile("v_exp_f32 %0, %1\ns_nop 1" : "=v"(r) : "v"(x)); return r;
}
#endif
#if __has_builtin(__builtin_amdgcn_sqrtf)
#define SQRTF_(x) __builtin_amdgcn_sqrtf(x)
#else
__device__ __forceinline__ float SQRTF_(float x) {
    float r; asm volatile("v_sqrt_f32 %0, %1\ns_nop 1" : "=v"(r) : "v"(x)); return r;
}
#endif

__device__ __forceinline__ unsigned short f2bf(float f) {
    unsigned u = __float_as_uint(f);
    u += 0x7fffu + ((u >> 16) & 1u);      // RNE
    return (unsigned short)(u >> 16);
}

// hi/lo bf16 split: v ≈ hi + lo with ~2^-17 relative residual
__device__ __forceinline__ void split2(float v, unsigned short& h, unsigned short& l) {
    h = f2bf(v);
    float fh = __uint_as_float((unsigned)h << 16);
    l = f2bf(v - fh);
}

// pack 2 f32 -> u32 of 2 bf16 (lo = first) — compiles to v_cvt_pk_bf16_f32
__device__ __forceinline__ unsigned pk2(float lo, float hi) {
    union { __hip_bfloat162 h2; unsigned u; } cvt;
    cvt.h2 = __float22bfloat162_rn(make_float2(lo, hi));
    return cvt.u;
}

// global(per-lane) -> LDS(wave-uniform base + lane*16) direct 16B copy
__device__ __forceinline__ void stage16(const void* g, void* l, int lane) {
#if __has_builtin(__builtin_amdgcn_global_load_lds)
    __builtin_amdgcn_global_load_lds((const __attribute__((address_space(1))) void*)g,
                                     (__attribute__((address_space(3))) void*)l, 16, 0, 0);
#else
    *(uint4*)((char*)l + lane * 16) = *(const uint4*)g;
#endif
}

// ---------------- kernel 1: weight transposes + pos MFMA-fragment tables ----------------
// Fragment-major, K=32 zero-padded tables (1 KB per 16-row block; koct 2,3 zero):
//   AfT[bh][jblk][koct][row][8]: j-side A-frag, slots(k=0..15) =
//     [xh,xh,xl, yh,yh,yl, zh,zh,zl, sh,sl,1, ah,al,1, 0]
//   BdT[b][iblk][koct][row][8]:  i-side d2 B-frag, slots =
//     [m2xh,m2xl,m2xh, m2yh,m2yl,m2yh, m2zh,m2zl,m2zh, 1,1,sh, 0,0,sl, 0]
// d2 = |pj|^2 + |pi|^2 - 2 pj·pi (split products, ~2^-16 rel); lin = aj = log2e*(w_h·pj).
// Per-i terms and bias cancel exactly through softmax normalization — omitted.
__global__ __launch_bounds__(256) void k_convert(
    const float* __restrict__ Wqk, const float* __restrict__ Wv,
    const float* __restrict__ Wpj, const float* __restrict__ coords,
    const float* __restrict__ W_pos,
    unsigned short* __restrict__ Wqk_t, unsigned short* __restrict__ Wv_t,
    unsigned short* __restrict__ Wp_t,
    unsigned short* __restrict__ AfT, unsigned short* __restrict__ BdT)
{
    __shared__ unsigned short T[64 * 72];
    const int bid = blockIdx.x, tid = threadIdx.x;
    if (bid < 64) {
        const float* src; unsigned short* dst; int N_, kt, nt;
        if (bid < 32)      { src = Wqk; dst = Wqk_t; N_ = 512; kt = bid & 3; nt = bid >> 2; }
        else if (bid < 48) { int t = bid - 32; src = Wv;  dst = Wv_t; N_ = 256; kt = t & 3; nt = t >> 2; }
        else               { int t = bid - 48; src = Wpj; dst = Wp_t; N_ = 256; kt = t & 3; nt = t >> 2; }
        const int kr = tid >> 2, seg = tid & 3;
        #pragma unroll
        for (int u = 0; u < 4; ++u) {
            float4 v = *(const float4*)(src + (kt * 64 + kr) * N_ + nt * 64 + seg * 16 + u * 4);
            T[(seg * 16 + u * 4 + 0) * 72 + kr] = f2bf(v.x);
            T[(seg * 16 + u * 4 + 1) * 72 + kr] = f2bf(v.y);
            T[(seg * 16 + u * 4 + 2) * 72 + kr] = f2bf(v.z);
            T[(seg * 16 + u * 4 + 3) * 72 + kr] = f2bf(v.w);
        }
        __syncthreads();
        const int n = tid >> 2, s2 = tid & 3;
        uint4 a = *(uint4*)&T[n * 72 + s2 * 16];
        uint4 b2 = *(uint4*)&T[n * 72 + s2 * 16 + 8];
        *(uint4*)(dst + (nt * 64 + n) * 256 + kt * 64 + s2 * 16) = a;
        *(uint4*)(dst + (nt * 64 + n) * 256 + kt * 64 + s2 * 16 + 8) = b2;
    } else if (bid < 96) {
        // AfT for bh = bid-64
        const int bh = bid - 64, b = bh >> 3, h = bh & 7;
        const float wxl = W_pos[0 * 8 + h] * LOG2E;
        const float wyl = W_pos[1 * 8 + h] * LOG2E;
        const float wzl = W_pos[2 * 8 + h] * LOG2E;
        const uint4 z = {0, 0, 0, 0};
        for (int j = tid; j < 1024; j += 256) {
            float x = coords[(b * 1024 + j) * 3 + 0];
            float y = coords[(b * 1024 + j) * 3 + 1];
            float z3 = coords[(b * 1024 + j) * 3 + 2];
            float s = fmaf(x, x, fmaf(y, y, z3 * z3));
            float a = fmaf(wzl, z3, fmaf(wyl, y, wxl * x));
            unsigned short xh, xl, yh, yl, zh, zl, sh, sl, ah, al;
            split2(x, xh, xl); split2(y, yh, yl); split2(z3, zh, zl);
            split2(s, sh, sl); split2(a, ah, al);
            unsigned short o[16] = { xh, xh, xl,  yh, yh, yl,  zh, zh, zl,
                                     sh, sl, ONEBF,  ah, al, ONEBF, 0 };
            unsigned short* blk = AfT + (size_t)bh * 32768 + (j >> 4) * 512;
            *(uint4*)(blk + (j & 15) * 8)       = ((uint4*)o)[0];   // koct0 (k=0..7)
            *(uint4*)(blk + 128 + (j & 15) * 8) = ((uint4*)o)[1];   // koct1 (k=8..15)
            *(uint4*)(blk + 256 + (j & 15) * 8) = z;                // koct2 zero
            *(uint4*)(blk + 384 + (j & 15) * 8) = z;                // koct3 zero
        }
    } else {
        // BdT for b = bid-96
        const int b = bid - 96;
        const uint4 z = {0, 0, 0, 0};
        for (int i = tid; i < 1024; i += 256) {
            float x = coords[(b * 1024 + i) * 3 + 0];
            float y = coords[(b * 1024 + i) * 3 + 1];
            float z3 = coords[(b * 1024 + i) * 3 + 2];
            float s = fmaf(x, x, fmaf(y, y, z3 * z3));
            unsigned short m2xh, m2xl, m2yh, m2yl, m2zh, m2zl, sh, sl;
            split2(-2.0f * x, m2xh, m2xl);
            split2(-2.0f * y, m2yh, m2yl);
            split2(-2.0f * z3, m2zh, m2zl);
            split2(s, sh, sl);
            unsigned short o[16] = { m2xh, m2xl, m2xh,  m2yh, m2yl, m2yh,  m2zh, m2zl, m2zh,
                                     ONEBF, ONEBF, sh,  0, 0, sl, 0 };
            unsigned short* blk = BdT + (size_t)b * 32768 + (i >> 4) * 512;
            *(uint4*)(blk + (i & 15) * 8)       = ((uint4*)o)[0];
            *(uint4*)(blk + 128 + (i & 15) * 8) = ((uint4*)o)[1];
            *(uint4*)(blk + 256 + (i & 15) * 8) = z;
            *(uint4*)(blk + 384 + (i & 15) * 8) = z;
        }
    }
}

// ---------------- kernel 2: QKV projection GEMM (M=4096, N=768, K=256) ----------------
// A staged from f32 x with in-flight cvt; B via gload_lds. q pre-scaled by SCALE*log2e.
// v written j-octet-subtiled per bh: element (j,d) at [(j>>3)*32 + d]*8 + (j&7).
__global__ __launch_bounds__(256) void k_qkv(
    const float* __restrict__ x,
    const unsigned short* __restrict__ Wqk_t,
    const unsigned short* __restrict__ Wv_t,
    unsigned short* __restrict__ q_ws, unsigned short* __restrict__ k_ws,
    unsigned short* __restrict__ v_ws)
{
    __shared__ unsigned short Al[64 * 64];   // [r][64], 128B rows, 16B-unit XOR swizzle u^(r&7)
    __shared__ unsigned short Bl[64 * 64];
    const int tid = threadIdx.x;
    const int n0 = blockIdx.x * 64;
    const int row0 = blockIdx.y * 64;
    const int w = tid >> 6, lane = tid & 63;
    const int lhi = lane >> 4, llo = lane & 15;
    const unsigned short* Bsrc = (n0 < 512) ? (Wqk_t + n0 * 256) : (Wv_t + (n0 - 512) * 256);

    const int sr = lane >> 3, sc = lane & 7;
    const int scx = sc ^ sr;                           // pre-swizzled source column unit

    f32x4_t acc[4] = {};
    for (int kc = 0; kc < 4; ++kc) {
        #pragma unroll
        for (int s = 0; s < 2; ++s) {
            int chunk = w * 2 + s;
            int r = chunk * 8 + sr;
            const float* ax = x + (row0 + r) * 256 + kc * 64 + scx * 8;
            float4 a0 = *(const float4*)ax, a1 = *(const float4*)(ax + 4);
            uint4 pk;
            pk.x = pk2(a0.x, a0.y); pk.y = pk2(a0.z, a0.w);
            pk.z = pk2(a1.x, a1.y); pk.w = pk2(a1.z, a1.w);
            *(uint4*)(&Al[r * 64 + sc * 8]) = pk;
            stage16(Bsrc + r * 256 + kc * 64 + scx * 8, &Bl[chunk * 512], lane);
        }
        __syncthreads();
        #pragma unroll
        for (int ks = 0; ks < 2; ++ks) {
            int ua = ((ks * 4 + lhi) ^ (llo & 7)) * 8;
            bf16x8_t a = *(const bf16x8_t*)(&Al[(w * 16 + llo) * 64 + ua]);
            #pragma unroll
            for (int nt = 0; nt < 4; ++nt) {
                bf16x8_t b = *(const bf16x8_t*)(&Bl[(nt * 16 + llo) * 64 + ua]);
                acc[nt] = __builtin_amdgcn_mfma_f32_16x16x32_bf16(a, b, acc[nt], 0, 0, 0);
            }
        }
        __syncthreads();
    }
    constexpr float QSC = (float)(1.4426950408889634 / 5.656854249492380195206754896838);
    #pragma unroll
    for (int nt = 0; nt < 4; ++nt) {
        int ng = n0 + nt * 16 + llo;
        if (ng < 512) {
            #pragma unroll
            for (int r = 0; r < 4; ++r) {
                int ig = row0 + w * 16 + lhi * 4 + r;
                float val = acc[nt][r];
                int b = ig >> 10, i = ig & 1023;
                if (ng < 256) {
                    int h = ng >> 5, d = ng & 31;
                    q_ws[((b * 8 + h) * 1024 + i) * 32 + d] = f2bf(val * QSC);
                } else {
                    int c = ng - 256, h = c >> 5, d = c & 31;
                    k_ws[((b * 8 + h) * 1024 + i) * 32 + d] = f2bf(val);
                }
            }
        } else {
            // V: pack 4 consecutive-i bf16 -> one uint2, subtiled layout
            int c = ng - 512, h = c >> 5, d = c & 31;
            int i0 = row0 + w * 16 + lhi * 4;          // (i0 & 7) == (lhi&1)*4
            int b = i0 >> 10, i = i0 & 1023;
            uint2 vv;
            vv.x = pk2(acc[nt][0], acc[nt][1]);
            vv.y = pk2(acc[nt][2], acc[nt][3]);
            *(uint2*)(v_ws + (size_t)(b * 8 + h) * 32768 + ((i >> 3) * 32 + d) * 8 + (i & 7)) = vv;
        }
    }
}

// ---------------- kernel 3: fused dual-softmax attention — pos geometry on MFMA ----------------
// grid: 512 blocks = 32 bh x 16 it (XCD-swizzled); 512 threads = 8 waves (4 wi x 2 wj)
// d2 and lin computed by MFMA from fragment-major zero-padded tables; per-entry VALU is
// max/sqrt/fma/exp2 only. Zero barriers in the main loop.
__global__ __launch_bounds__(512, 4) void k_attn(
    const unsigned short* __restrict__ q_ws,
    const unsigned short* __restrict__ k_ws,
    const unsigned short* __restrict__ v_ws,
    const unsigned short* __restrict__ AfT,
    const unsigned short* __restrict__ BdT,
    const float* __restrict__ W_pos,
    const float* __restrict__ gating,
    unsigned short* __restrict__ o_ws)
{
    __shared__ __align__(16) unsigned short Wp[8 * 16 * 64];   // 16 KB per-wave eP tiles
    __shared__ __align__(16) unsigned short Wq[8 * 16 * 64];   // 16 KB per-wave eq tiles

    const int tid = threadIdx.x;
    const int bid = blockIdx.x;
    const int xcd = bid & 7, s = bid >> 3;
    const int bh = xcd * 4 + (s >> 4);
    const int it = s & 15;
    const int b = bh >> 3, h = bh & 7;

    const int w = tid >> 6, lane = tid & 63;
    const int wi = w & 3, wj = w >> 2;
    const int lhi = lane >> 4, llo = lane & 15;

    const float wdl = W_pos[3 * 8 + h] * LOG2E;

    const int i_base = it * 64 + wi * 16;
    // qf = B-frag of swapped QK^T: lane llo = i, elems d = lhi*8+e
    bf16x8_t qf = *(const bf16x8_t*)(q_ws + (bh * 1024 + i_base + llo) * 32 + lhi * 8);
    // i-side d2 B-frag (fragment-major table: [iblk][koct=lhi][row=llo][8])
    bf16x8_t Bd2 = *(const bf16x8_t*)(BdT + (size_t)b * 32768 +
                                      (it * 4 + wi) * 512 + (lhi * 16 + llo) * 8);
    // lin-picker B-frag: k slots 12,13 = 1.0 (pairs A's ah,al)
    bf16x8_t Blin = {};
    if (lhi == 1) { Blin[4] = (short)ONEBF; Blin[5] = (short)ONEBF; }

    bf16x8_t ones;
    #pragma unroll
    for (int e = 0; e < 8; ++e) ones[e] = (short)0x3F80;   // bf16 1.0

    f32x4_t accP[2] = {}, accQ[2] = {};
    f32x4_t accLp = {}, accLq = {};

    const unsigned short* kbase = k_ws + (size_t)bh * 32768;
    const unsigned short* vbase = v_ws + (size_t)bh * 32768;
    const unsigned short* abase = AfT + (size_t)bh * 32768;

    for (int t = 0; t < 8; ++t) {
        const int j0 = wj * 512 + t * 64;
        // --- issue K / Af / V frag loads (all fully coalesced, L1/L2-resident) ---
        bf16x8_t kf[4], af[4], vf[4];
        #pragma unroll
        for (int jq = 0; jq < 4; ++jq) {
            kf[jq] = *(const bf16x8_t*)(kbase + (j0 + jq * 16 + llo) * 32 + lhi * 8);
            af[jq] = *(const bf16x8_t*)(abase + (wj * 32 + t * 4 + jq) * 512 +
                                        (lhi * 16 + llo) * 8);
        }
        #pragma unroll
        for (int jb = 0; jb < 2; ++jb)
            #pragma unroll
            for (int dt = 0; dt < 2; ++dt)
                vf[jb * 2 + dt] = *(const bf16x8_t*)(vbase +
                    ((j0 + jb * 32 + lhi * 8) >> 3) * 256 + (dt * 16 + llo) * 8);

        // --- swapped QK^T: sv = mfma(K,Q) -> lane: i=llo, j=jq*16+lhi*4+r ---
        #pragma unroll
        for (int jq = 0; jq < 4; ++jq) {
            f32x4_t zero = {};
            f32x4_t sv = __builtin_amdgcn_mfma_f32_16x16x32_bf16(kf[jq], qf, zero, 0, 0, 0);
            uint2 uP;
            uP.x = pk2(EXP2F_(sv[0]), EXP2F_(sv[1]));
            uP.y = pk2(EXP2F_(sv[2]), EXP2F_(sv[3]));
            int off = (w * 16 + llo) * 64 +
                      (((jq * 2 + (lhi >> 1)) ^ (llo & 7)) * 8) + (lhi & 1) * 4;
            *(uint2*)(&Wp[off]) = uP;
        }

        // --- pos: d2/lin via MFMA (same D mapping as sv), then max/sqrt/fma/exp2 ---
        #pragma unroll
        for (int jq = 0; jq < 4; ++jq) {
            f32x4_t z1 = {}, z2 = {};
            f32x4_t d2v = __builtin_amdgcn_mfma_f32_16x16x32_bf16(af[jq], Bd2, z1, 0, 0, 0);
            f32x4_t lnv = __builtin_amdgcn_mfma_f32_16x16x32_bf16(af[jq], Blin, z2, 0, 0, 0);
            float e0 = EXP2F_(fmaf(wdl, SQRTF_(fmaxf(d2v[0], 0.f)), lnv[0]));
            float e1 = EXP2F_(fmaf(wdl, SQRTF_(fmaxf(d2v[1], 0.f)), lnv[1]));
            float e2 = EXP2F_(fmaf(wdl, SQRTF_(fmaxf(d2v[2], 0.f)), lnv[2]));
            float e3 = EXP2F_(fmaf(wdl, SQRTF_(fmaxf(d2v[3], 0.f)), lnv[3]));
            uint2 uQ;
            uQ.x = pk2(e0, e1);
            uQ.y = pk2(e2, e3);
            int off = (w * 16 + llo) * 64 +
                      (((jq * 2 + (lhi >> 1)) ^ (llo & 7)) * 8) + (lhi & 1) * 4;
            *(uint2*)(&Wq[off]) = uQ;
        }

        // --- PV + L-rows (bP/bQ via same-wave LDS exchange; compiler inserts lgkmcnt) ---
        #pragma unroll
        for (int jb = 0; jb < 2; ++jb) {
            int uu = ((jb * 4 + lhi) ^ (llo & 7)) * 8;
            bf16x8_t bP = *(const bf16x8_t*)(&Wp[(w * 16 + llo) * 64 + uu]);
            bf16x8_t bQ = *(const bf16x8_t*)(&Wq[(w * 16 + llo) * 64 + uu]);
            accLp = __builtin_amdgcn_mfma_f32_16x16x32_bf16(ones, bP, accLp, 0, 0, 0);
            accLq = __builtin_amdgcn_mfma_f32_16x16x32_bf16(ones, bQ, accLq, 0, 0, 0);
            accP[0] = __builtin_amdgcn_mfma_f32_16x16x32_bf16(vf[jb * 2 + 0], bP, accP[0], 0, 0, 0);
            accP[1] = __builtin_amdgcn_mfma_f32_16x16x32_bf16(vf[jb * 2 + 1], bP, accP[1], 0, 0, 0);
            accQ[0] = __builtin_amdgcn_mfma_f32_16x16x32_bf16(vf[jb * 2 + 0], bQ, accQ[0], 0, 0, 0);
            accQ[1] = __builtin_amdgcn_mfma_f32_16x16x32_bf16(vf[jb * 2 + 1], bQ, accQ[1], 0, 0, 0);
        }
    }

    // --- epilogue: cross-half combine in LDS (reuse Wp/Wq), gate+normalize, write o_ws ---
    __syncthreads();             // all waves done with Wp/Wq
    float* red = (float*)Wp;     // 4096 f32: [wi*64+lane][16]
    float* LPQ = (float*)Wq;     // [0..63] Lp, [64..127] Lq
    if (wj == 1) {
        float* pr = red + (wi * 64 + lane) * 16;
        *(f32x4_t*)(pr + 0) = accP[0]; *(f32x4_t*)(pr + 4)  = accP[1];
        *(f32x4_t*)(pr + 8) = accQ[0]; *(f32x4_t*)(pr + 12) = accQ[1];
        if (lhi == 0) { LPQ[wi * 16 + llo] = accLp[0]; LPQ[64 + wi * 16 + llo] = accLq[0]; }
    }
    __syncthreads();
    if (wj == 0) {
        const float* pr = red + (wi * 64 + lane) * 16;
        float Lp = accLp[0] + LPQ[wi * 16 + llo];
        float Lq = accLq[0] + LPQ[64 + wi * 16 + llo];
        float sig = 1.0f / (1.0f + __expf(-gating[h]));
        float ca = (1.0f - sig) / Lp, cb2 = sig / Lq;
        int rowg = b * 1024 + it * 64 + wi * 16 + llo;
        #pragma unroll
        for (int dt = 0; dt < 2; ++dt) {
            float o0 = ca * (accP[dt][0] + pr[dt * 4 + 0]) + cb2 * (accQ[dt][0] + pr[8 + dt * 4 + 0]);
            float o1 = ca * (accP[dt][1] + pr[dt * 4 + 1]) + cb2 * (accQ[dt][1] + pr[8 + dt * 4 + 1]);
            float o2 = ca * (accP[dt][2] + pr[dt * 4 + 2]) + cb2 * (accQ[dt][2] + pr[8 + dt * 4 + 2]);
            float o3 = ca * (accP[dt][3] + pr[dt * 4 + 3]) + cb2 * (accQ[dt][3] + pr[8 + dt * 4 + 3]);
            uint2 uu;
            uu.x = pk2(o0, o1); uu.y = pk2(o2, o3);
            *(uint2*)(o_ws + (size_t)rowg * 256 + h * 32 + dt * 16 + lhi * 4) = uu;
        }
    }
}

// ---------------- kernel 4: output projection GEMM (M=4096, N=256, K=256) + bias ----------------
__global__ __launch_bounds__(256) void k_proj(
    const unsigned short* __restrict__ A,
    const unsigned short* __restrict__ Bt,
    const float* __restrict__ bias,
    float* __restrict__ out)
{
    __shared__ unsigned short Al[64 * 64];
    __shared__ unsigned short Bl[64 * 64];
    const int tid = threadIdx.x;
    const int n0 = blockIdx.x * 64;
    const int row0 = blockIdx.y * 64;
    const int w = tid >> 6, lane = tid & 63;
    const int lhi = lane >> 4, llo = lane & 15;
    const int sr = lane >> 3, sc = lane & 7;
    const int scx = sc ^ sr;

    f32x4_t acc[4] = {};
    for (int kc = 0; kc < 4; ++kc) {
        #pragma unroll
        for (int s = 0; s < 2; ++s) {
            int chunk = w * 2 + s;
            int r = chunk * 8 + sr;
            stage16(A + (row0 + r) * 256 + kc * 64 + scx * 8, &Al[chunk * 512], lane);
            stage16(Bt + (n0 + r) * 256 + kc * 64 + scx * 8, &Bl[chunk * 512], lane);
        }
        __syncthreads();
        #pragma unroll
        for (int ks = 0; ks < 2; ++ks) {
            int ua = ((ks * 4 + lhi) ^ (llo & 7)) * 8;
            bf16x8_t a = *(const bf16x8_t*)(&Al[(w * 16 + llo) * 64 + ua]);
            #pragma unroll
            for (int nt = 0; nt < 4; ++nt) {
                bf16x8_t b = *(const bf16x8_t*)(&Bl[(nt * 16 + llo) * 64 + ua]);
                acc[nt] = __builtin_amdgcn_mfma_f32_16x16x32_bf16(a, b, acc[nt], 0, 0, 0);
            }
        }
        __syncthreads();
    }
    #pragma unroll
    for (int nt = 0; nt < 4; ++nt) {
        int ng = n0 + nt * 16 + llo;
        float bv = bias[ng];
        #pragma unroll
        for (int r = 0; r < 4; ++r) {
            int ig = row0 + w * 16 + lhi * 4 + r;
            out[ig * 256 + ng] = acc[nt][r] + bv;
        }
    }
}

// ---------------- launcher ----------------
extern "C" void kernel_launch(void* const* d_in, const int* in_sizes, int n_in,
                              void* d_out, int out_size, void* d_ws, size_t ws_size,
                              hipStream_t stream)
{
    const float* x    = (const float*)d_in[0];
    const float* vc   = (const float*)d_in[1];
    const float* Wqk  = (const float*)d_in[2];
    const float* Wv   = (const float*)d_in[3];
    const float* Wpj  = (const float*)d_in[4];
    const float* bpj  = (const float*)d_in[5];
    const float* Wpos = (const float*)d_in[6];
    const float* bpos = (const float*)d_in[7];   // bias cancels in normalization — unused
    const float* gat  = (const float*)d_in[8];
    float* out = (float*)d_out;
    (void)bpos;

    char* ws = (char*)d_ws;
    unsigned short* Wqk_t = (unsigned short*)(ws + 0);          // 256 KB
    unsigned short* Wv_t  = (unsigned short*)(ws + 262144);     // 128 KB
    unsigned short* Wp_t  = (unsigned short*)(ws + 393216);     // 128 KB
    unsigned short* q_ws  = (unsigned short*)(ws + 524288);     // 2 MB
    unsigned short* k_ws  = (unsigned short*)(ws + 2621440);    // 2 MB
    unsigned short* v_ws  = (unsigned short*)(ws + 4718592);    // 2 MB (j-octet subtiled)
    unsigned short* o_ws  = (unsigned short*)(ws + 6815744);    // 2 MB
    unsigned short* AfT   = (unsigned short*)(ws + 8912896);    // 2 MB  j-side pos frags
    unsigned short* BdT   = (unsigned short*)(ws + 11010048);   // 256 KB i-side pos frags

    hipLaunchKernelGGL(k_convert, dim3(100), dim3(256), 0, stream,
                       Wqk, Wv, Wpj, vc, Wpos, Wqk_t, Wv_t, Wp_t, AfT, BdT);
    hipLaunchKernelGGL(k_qkv, dim3(12, 64), dim3(256), 0, stream,
                       x, Wqk_t, Wv_t, q_ws, k_ws, v_ws);
    hipLaunchKernelGGL(k_attn, dim3(512), dim3(512), 0, stream,
                       q_ws, k_ws, v_ws, AfT, BdT, Wpos, gat, o_ws);
    hipLaunchKernelGGL(k_proj, dim3(4, 64), dim3(256), 0, stream,
                       o_ws, Wp_t, bpj, out);
}